// Round 10
// baseline (128.917 us; speedup 1.0000x reference)
//
#include <hip/hip_runtime.h>

typedef unsigned short u16;
typedef unsigned char u8;
typedef unsigned int u32;
typedef float f32x4 __attribute__((ext_vector_type(4)));
typedef __bf16 bf16x8 __attribute__((ext_vector_type(8)));

#define SPB 6291456      // bytes per packed branch: B*N*C = 16*1024*384 (u8, 4 t-bits)

// ---- async global->LDS, 16B per lane, dest = wave-uniform base + lane*16 ----
__device__ __forceinline__ void gll16(const void* g, void* l) {
  __builtin_amdgcn_global_load_lds((const __attribute__((address_space(1))) void*)g,
                                   (__attribute__((address_space(3))) void*)l, 16, 0, 0);
}

// expand 8 packed spike-bytes (bit t) -> 8 bf16 {0,1}; perm+mul: (b0|b1<<16)*0x3F80
__device__ __forceinline__ uint4 expand8f(uint2 v, u32 t) {
  u32 a = (v.x >> t) & 0x01010101u;
  u32 b = (v.y >> t) & 0x01010101u;
  uint4 r;
  r.x = __builtin_amdgcn_perm(0u, a, 0x0C010C00u) * 0x3F80u;
  r.y = __builtin_amdgcn_perm(0u, a, 0x0C030C02u) * 0x3F80u;
  r.z = __builtin_amdgcn_perm(0u, b, 0x0C010C00u) * 0x3F80u;
  r.w = __builtin_amdgcn_perm(0u, b, 0x0C030C02u) * 0x3F80u;
  return r;
}

// ---------------- K0: weights -> bf16 (stacked q,k,v), BN params fused ----------------
__global__ __launch_bounds__(256) void k_convert(
    const float* __restrict__ qw, const float* __restrict__ kw,
    const float* __restrict__ vw, const float* __restrict__ pw,
    const float* __restrict__ qg, const float* __restrict__ qbt,
    const float* __restrict__ qm, const float* __restrict__ qv,
    const float* __restrict__ kg, const float* __restrict__ kbt,
    const float* __restrict__ km, const float* __restrict__ kv,
    const float* __restrict__ vg, const float* __restrict__ vbt,
    const float* __restrict__ vm, const float* __restrict__ vv,
    const float* __restrict__ pg, const float* __restrict__ pbt,
    const float* __restrict__ pm, const float* __restrict__ pv,
    const float* __restrict__ pbias,
    u16* __restrict__ Wstk, u16* __restrict__ Pw,
    float4* __restrict__ BNP, float4* __restrict__ PP) {
  int tid = blockIdx.x * 256 + threadIdx.x;
  if (tid < 442368) {               // Wstk[1152][384]
    int r = tid / 384, c = tid - r * 384;
    const float* src = (r < 384) ? qw : (r < 768) ? kw : vw;
    int rr = (r >= 768) ? r - 768 : (r >= 384) ? r - 384 : r;
    unsigned int u = __float_as_uint(src[rr * 384 + c]);
    u = (u + 0x7FFFu + ((u >> 16) & 1u)) >> 16;   // RNE to bf16
    Wstk[tid] = (u16)u;
  } else if (tid < 589824) {        // Pw[384][384]
    int i = tid - 442368;
    unsigned int u = __float_as_uint(pw[i]);
    u = (u + 0x7FFFu + ((u >> 16) & 1u)) >> 16;
    Pw[i] = (u16)u;
  } else if (tid < 590976) {        // BNP[1152] = {inv, mean, beta, -}
    int r = tid - 589824;
    int br = r / 384, ch = r - br * 384;
    const float* g  = (br == 0) ? qg  : (br == 1) ? kg  : vg;
    const float* bt = (br == 0) ? qbt : (br == 1) ? kbt : vbt;
    const float* m  = (br == 0) ? qm  : (br == 1) ? km  : vm;
    const float* va = (br == 0) ? qv  : (br == 1) ? kv  : vv;
    float inv = g[ch] / sqrtf(va[ch] + 1e-5f);
    BNP[r] = make_float4(inv, m[ch], bt[ch], 0.f);
  } else if (tid < 591360) {        // PP[384] = {inv, mean, beta, bias}
    int ch = tid - 590976;
    float inv = pg[ch] / sqrtf(pv[ch] + 1e-5f);
    PP[ch] = make_float4(inv, pm[ch], pbt[ch], pbias[ch]);
  }
}

// ---------------- K1: input LIF -> packed nibble xsb[(b*1024+n)*384 + c] --------------
__global__ __launch_bounds__(256) void k_lif_in(const float* __restrict__ x, u8* __restrict__ xsb) {
  const int nt = blockIdx.x, ct = blockIdx.y, b = blockIdx.z;
  const int tid = threadIdx.x;
  const int nj = tid & 63, cr = tid >> 6;
  const int c0 = ct * 64, n0 = nt * 64;
  __shared__ u32 nibs[64 * 65];     // [nj][c], +1-pad (u32) -> conflict-free
  float v[16];
  u32 nib[16];
  #pragma unroll
  for (int i = 0; i < 16; ++i) { v[i] = 0.f; nib[i] = 0u; }
  for (int t = 0; t < 4; ++t) {
    const float* xr = x + (((t * 16 + b) * 384 + c0 + cr) * 1024) + n0 + nj;
    #pragma unroll
    for (int it = 0; it < 16; ++it) {
      float xv = xr[it * 4096];
      float vv = v[it];
      float h = __fadd_rn(vv, __fmul_rn(__fsub_rn(xv, vv), 0.5f));  // v + (x-v)/2, exact order
      bool s = h >= 1.f;
      v[it] = s ? 0.f : h;
      nib[it] |= (s ? 1u : 0u) << t;
    }
  }
  #pragma unroll
  for (int it = 0; it < 16; ++it) nibs[nj * 65 + cr + it * 4] = nib[it];
  __syncthreads();
  const int n = tid >> 2, ch = tid & 3;
  u32 w0[4];
  #pragma unroll
  for (int q = 0; q < 4; ++q) {
    u32 acc = 0;
    #pragma unroll
    for (int i = 0; i < 4; ++i)
      acc |= (nibs[n * 65 + ch * 16 + q * 4 + i] & 0xFu) << (8 * i);
    w0[q] = acc;
  }
  *(uint4*)(xsb + ((size_t)(b * 1024 + n0 + n)) * 384 + c0 + ch * 16) =
      make_uint4(w0[0], w0[1], w0[2], w0[3]);
}

// ======================================================================================
// GEMM core v6 (phase-split): BM=128 c, BN=256 j (64 n x 4 t), K=384 full.
// X packed-resident in LDS (26 KB, 416B-padded rows), expanded on read (verified v5).
// W pipeline: 3 x 8KB buffers, 1 gll16/thread/tile, 2 tiles in flight, vmcnt(1).
// Each K-tile split into 2 phases of 8 MFMA with barriers between (m201-lite):
//   P0: vmcnt; BAR; issue W(t+2); A-expand x4; B ci0-1; 8 MFMA; BAR;
//   P1: B ci2-3; 8 MFMA; BAR;
// LDS total 51200 B -> 3 blocks/CU: 3 independent barrier groups drift & overlap pipes.
// ======================================================================================
#define XLDS_U16 13312                 // 26624 B X region (64 rows x 416 B)
#define WSLOT_U16 4096                 // 8 KB per W buffer slot

#define GISSUE(kt) gll16(Wp + (kt) * 32, &lds[XLDS_U16 + ((kt) % 3) * WSLOT_U16 + wst])

#define MFMA2CI(c0, c1) do { \
    _Pragma("unroll") \
    for (int ci = (c0); ci <= (c1); ++ci) { \
      bf16x8 bw_ = *(const bf16x8*)&wb_[(wcg * 64 + ci * 16 + l15) * 32 + swoff]; \
      _Pragma("unroll") \
      for (int ji = 0; ji < 4; ++ji) \
        acc[ji][ci] = __builtin_amdgcn_mfma_f32_16x16x32_bf16(ax[ji], bw_, acc[ji][ci], 0, 0, 0); \
    } \
  } while (0)

#define GSTEP(t, VN, ISS) do { \
    asm volatile("s_waitcnt vmcnt(" #VN ")" ::: "memory"); \
    __builtin_amdgcn_s_barrier(); \
    asm volatile("" ::: "memory"); \
    ISS; \
    const u8* xb_ = (const u8*)lds; \
    const u16* wb_ = &lds[XLDS_U16 + ((t) % 3) * WSLOT_U16]; \
    bf16x8 ax[4]; \
    _Pragma("unroll") \
    for (int ji = 0; ji < 4; ++ji) { \
      uint2 xr_ = *(const uint2*)(xb_ + (wjg * 16 + ji * 4 + d4) * 416 + (t) * 32 + g8); \
      uint4 e_ = expand8f(xr_, t_lane); \
      ax[ji] = *(bf16x8*)&e_; \
    } \
    __builtin_amdgcn_s_setprio(1); \
    MFMA2CI(0, 1); \
    __builtin_amdgcn_s_setprio(0); \
    __builtin_amdgcn_s_barrier(); \
    asm volatile("" ::: "memory"); \
    __builtin_amdgcn_s_setprio(1); \
    MFMA2CI(2, 3); \
    __builtin_amdgcn_s_setprio(0); \
    __builtin_amdgcn_s_barrier(); \
    asm volatile("" ::: "memory"); \
  } while (0)

#define GEMM_PIPELINE() do { \
    GISSUE(0); GISSUE(1); \
    GSTEP(0, 1, GISSUE(2)); \
    GSTEP(1, 1, GISSUE(3)); \
    GSTEP(2, 1, GISSUE(4)); \
    GSTEP(3, 1, GISSUE(5)); \
    GSTEP(4, 1, GISSUE(6)); \
    GSTEP(5, 1, GISSUE(7)); \
    GSTEP(6, 1, GISSUE(8)); \
    GSTEP(7, 1, GISSUE(9)); \
    GSTEP(8, 1, GISSUE(10)); \
    GSTEP(9, 1, GISSUE(11)); \
    GSTEP(10, 1, ); \
    GSTEP(11, 0, ); \
  } while (0)

// stage packed X strip (64 n x 384 B) into padded LDS rows (416 B), then sync
#define XSTAGE(XSRC) do { \
    const int xn_ = tid >> 3, xcp_ = tid & 7; \
    const u8* xs_ = (XSRC) + (size_t)(b * 1024 + jt * 64 + xn_) * 384 + xcp_ * 48; \
    u8* xd_ = (u8*)lds + xn_ * 416 + xcp_ * 48; \
    uint4 v0_ = *(const uint4*)(xs_); \
    uint4 v1_ = *(const uint4*)(xs_ + 16); \
    uint4 v2_ = *(const uint4*)(xs_ + 32); \
    *(uint4*)(xd_) = v0_; *(uint4*)(xd_ + 16) = v1_; *(uint4*)(xd_ + 32) = v2_; \
    __syncthreads(); \
  } while (0)

#define GEMM_SETUP() \
  const int tid = threadIdx.x; \
  const int w = tid >> 6, l = tid & 63; \
  const int wjg = w >> 1, wcg = w & 1; \
  const int l15 = tid & 15, g = l >> 4; \
  const int swoff = (g ^ ((l15 >> 1) & 3)) * 8; \
  const int wst = w * 512; \
  const int d4 = l15 >> 2, g8 = g * 8; \
  const u32 t_lane = (u32)(l15 & 3); \
  const int sch = (l & 3) ^ ((l >> 3) & 3); \
  f32x4 acc[4][4]; \
  { const f32x4 zero_ = {0.f, 0.f, 0.f, 0.f}; \
    _Pragma("unroll") \
    for (int ji = 0; ji < 4; ++ji) \
      _Pragma("unroll") \
      for (int ci = 0; ci < 4; ++ci) acc[ji][ci] = zero_; }

// ---------------- K2: qkv GEMM (one branch-panel per block) + BN + LIF -> sp nibbles --
__global__ __launch_bounds__(512, 4) void k_qkv(
    const u16* __restrict__ Wstk, const u8* __restrict__ xsb,
    const float4* __restrict__ BNP, u8* __restrict__ sp) {
  const int jt = blockIdx.x, mt = blockIdx.y, b = blockIdx.z;
  __shared__ u16 lds[25600];                      // 26624B X + 3x8KB W = 51200 B

  GEMM_SETUP();
  XSTAGE(xsb);

  const int m0 = mt * 128;                        // == (mt/3)*384 + (mt%3)*128 in Wstk
  const u16* Wp = Wstk + (size_t)(m0 + w * 16 + (l >> 2)) * 384 + sch * 8;

  GEMM_PIPELINE();

  // epilogue: BN + 4-step LIF (acc regs = t), pack 4 spike bits -> one u8
  const int br = mt / 3;
  const int cb = (mt - br * 3) * 128;
  const int n_base = b * 1024 + jt * 64 + wjg * 16 + g;
  u8* spW = sp + (size_t)br * SPB;
  #pragma unroll
  for (int ci = 0; ci < 4; ++ci) {
    const int c_loc = wcg * 64 + ci * 16 + l15;
    float4 pr = BNP[br * 384 + cb + c_loc];       // direct L2 load (PRM LDS removed)
    #pragma unroll
    for (int ji = 0; ji < 4; ++ji) {
      f32x4 a = acc[ji][ci];
      u32 bits = 0;
      float vv = 0.f;
      #pragma unroll
      for (int t = 0; t < 4; ++t) {
        float z = __fadd_rn(__fmul_rn(__fsub_rn(a[t], pr.y), pr.x), pr.z);  // BN, ref order
        float h = __fadd_rn(vv, __fmul_rn(__fsub_rn(z, vv), 0.5f));          // LIF step
        bool s = h >= 1.f;
        vv = s ? 0.f : h;
        bits |= (s ? 1u : 0u) << t;
      }
      spW[(size_t)(n_base + ji * 4) * 384 + cb + c_loc] = (u8)bits;
    }
  }
}

// ---------------- K3: attn = sum_ch(k&v) per head, LIF(0.5) -> xpb = q & mask ---------
__global__ __launch_bounds__(256) void k_attn(const u8* __restrict__ sp, u8* __restrict__ xpb) {
  const int gw = blockIdx.x * 4 + (threadIdx.x >> 6);
  const int l = threadIdx.x & 63;
  const int b = gw >> 10, n = gw & 1023;
  const u8* qB = sp;
  const u8* kB = sp + SPB;
  const u8* vB = sp + 2 * SPB;
  const int base = (b * 1024 + n) * 384 + l * 6;   // byte index; lane covers 6 channels
  u16 qu[3], ku[3], vu[3];
  #pragma unroll
  for (int i = 0; i < 3; ++i) {
    qu[i] = *(const u16*)(qB + base + 2 * i);
    ku[i] = *(const u16*)(kB + base + 2 * i);
    vu[i] = *(const u16*)(vB + base + 2 * i);
  }
  u32 s = 0;                        // 4 per-t byte sums packed in a u32
  #pragma unroll
  for (int i = 0; i < 3; ++i) {
    u32 a = (u32)(ku[i] & vu[i]);
    #pragma unroll
    for (int t = 0; t < 4; ++t) {
      u32 x = (a >> t) & 0x0101u;
      s += ((x + (x >> 8)) & 3u) << (8 * t);
    }
  }
  s += __shfl_xor(s, 1);
  s += __shfl_xor(s, 2);
  s += __shfl_xor(s, 4);            // 8 lanes == one 48-channel head; bytes <= 48
  float v = 0.f;
  u32 m8 = 0;
  #pragma unroll
  for (int t = 0; t < 4; ++t) {
    float attn = (float)((s >> (8 * t)) & 0xFFu);
    float h = __fadd_rn(v, __fmul_rn(__fsub_rn(attn, v), 0.5f));
    bool sk = h >= 0.5f;
    v = sk ? 0.f : h;
    m8 |= (sk ? 1u : 0u) << t;
  }
  const u16 mm = (u16)(m8 * 0x0101u);
  u16* dst = (u16*)(xpb + base);
  #pragma unroll
  for (int i = 0; i < 3; ++i) dst[i] = qu[i] & mm;
}

// ---------------- K4: P GEMM (one 128-c panel per block) + bias + BN -> out fp32 ------
__global__ __launch_bounds__(512, 4) void k_proj(
    const u16* __restrict__ Pw, const u8* __restrict__ xpb,
    const float4* __restrict__ PP, float* __restrict__ out) {
  const int jt = blockIdx.x, mt = blockIdx.y, b = blockIdx.z;
  __shared__ u16 lds[25600];

  GEMM_SETUP();
  XSTAGE(xpb);

  const int m0 = mt * 128;
  const u16* Wp = Pw + (size_t)(m0 + w * 16 + (l >> 2)) * 384 + sch * 8;

  GEMM_PIPELINE();

  __syncthreads();                                 // all waves done with LDS buffers
  float* scr = (float*)lds;                        // 128 x 68-padded f32 tile (34.8 KB)
  const int n0im = jt * 64;
  float4 prc[4];
  #pragma unroll
  for (int ci = 0; ci < 4; ++ci) prc[ci] = PP[m0 + wcg * 64 + ci * 16 + l15];

  #pragma unroll
  for (int t = 0; t < 4; ++t) {
    #pragma unroll
    for (int ci = 0; ci < 4; ++ci) {
      const int c_loc = wcg * 64 + ci * 16 + l15;
      float4 pr = prc[ci];
      #pragma unroll
      for (int ji = 0; ji < 4; ++ji) {
        const int n_loc = wjg * 16 + ji * 4 + g;
        float zz = __fadd_rn(acc[ji][ci][t], pr.w);                        // + bias
        zz = __fadd_rn(__fmul_rn(__fsub_rn(zz, pr.y), pr.x), pr.z);        // BN, ref order
        scr[c_loc * 68 + n_loc] = zz;
      }
    }
    __syncthreads();
    #pragma unroll
    for (int it = 0; it < 4; ++it) {
      int slot = tid + it * 512;                   // 2048 slots = 128 rows x 16 float4
      int c = slot >> 4, li = slot & 15;
      float4 val = *(const float4*)&scr[c * 68 + li * 4];
      *(float4*)&out[(((size_t)(t * 16 + b) * 384) + m0 + c) * 1024 + n0im + li * 4] = val;
    }
    __syncthreads();
  }
}

extern "C" void kernel_launch(void* const* d_in, const int* in_sizes, int n_in,
                              void* d_out, int out_size, void* d_ws, size_t ws_size,
                              hipStream_t stream) {
  (void)in_sizes; (void)n_in; (void)out_size; (void)ws_size;
  const float* x   = (const float*)d_in[0];
  const float* qw  = (const float*)d_in[1];
  const float* qg  = (const float*)d_in[2];
  const float* qbt = (const float*)d_in[3];
  const float* qm  = (const float*)d_in[4];
  const float* qv  = (const float*)d_in[5];
  const float* kw  = (const float*)d_in[6];
  const float* kg  = (const float*)d_in[7];
  const float* kbt = (const float*)d_in[8];
  const float* km  = (const float*)d_in[9];
  const float* kv  = (const float*)d_in[10];
  const float* vw  = (const float*)d_in[11];
  const float* vg  = (const float*)d_in[12];
  const float* vbt = (const float*)d_in[13];
  const float* vm  = (const float*)d_in[14];
  const float* vv  = (const float*)d_in[15];
  const float* pw  = (const float*)d_in[16];
  const float* pg  = (const float*)d_in[17];
  const float* pbt = (const float*)d_in[18];
  const float* pm  = (const float*)d_in[19];
  const float* pv  = (const float*)d_in[20];
  const float* pbias = (const float*)d_in[21];

  char* ws = (char*)d_ws;
  u8*  xsb   = (u8*)ws;                     // input spikes, packed nibbles (6.3 MB)
  u8*  sp    = (u8*)(ws + 6291456);         // q,k,v spike nibbles (3 x 6.3 MB)
  u8*  xpb   = (u8*)(ws + 25165824);        // q&attn spikes, packed nibbles (6.3 MB)
  u16* Wstk  = (u16*)(ws + 31457280);       // [1152][384] bf16
  u16* Pw    = (u16*)(ws + 32342016);       // [384][384] bf16
  float4* BNP = (float4*)(ws + 32636928);   // [1152]
  float4* PP  = (float4*)(ws + 32655360);   // [384]

  k_convert<<<2310, 256, 0, stream>>>(qw, kw, vw, pw, qg, qbt, qm, qv, kg, kbt, km, kv,
                                      vg, vbt, vm, vv, pg, pbt, pm, pv, pbias,
                                      Wstk, Pw, BNP, PP);
  k_lif_in<<<dim3(16, 6, 16), 256, 0, stream>>>(x, xsb);
  k_qkv<<<dim3(16, 9, 16), 512, 0, stream>>>(Wstk, xsb, BNP, sp);
  k_attn<<<4096, 256, 0, stream>>>(sp, xpb);
  k_proj<<<dim3(16, 3, 16), 512, 0, stream>>>(Pw, xpb, PP, (float*)d_out);
}

// Round 11
// 128.651 us; speedup vs baseline: 1.0021x; 1.0021x over previous
//
#include <hip/hip_runtime.h>

typedef unsigned short u16;
typedef unsigned char u8;
typedef unsigned int u32;
typedef float f32x4 __attribute__((ext_vector_type(4)));
typedef __bf16 bf16x8 __attribute__((ext_vector_type(8)));

#define SPB 6291456      // bytes per packed branch: B*N*C = 16*1024*384 (u8, 4 t-bits)

// ---- async global->LDS, 16B per lane, dest = wave-uniform base + lane*16 ----
__device__ __forceinline__ void gll16(const void* g, void* l) {
  __builtin_amdgcn_global_load_lds((const __attribute__((address_space(1))) void*)g,
                                   (__attribute__((address_space(3))) void*)l, 16, 0, 0);
}

// expand 8 packed spike-bytes (bit t) -> 8 bf16 {0,1}; perm+mul: (b0|b1<<16)*0x3F80
__device__ __forceinline__ uint4 expand8f(uint2 v, u32 t) {
  u32 a = (v.x >> t) & 0x01010101u;
  u32 b = (v.y >> t) & 0x01010101u;
  uint4 r;
  r.x = __builtin_amdgcn_perm(0u, a, 0x0C010C00u) * 0x3F80u;
  r.y = __builtin_amdgcn_perm(0u, a, 0x0C030C02u) * 0x3F80u;
  r.z = __builtin_amdgcn_perm(0u, b, 0x0C010C00u) * 0x3F80u;
  r.w = __builtin_amdgcn_perm(0u, b, 0x0C030C02u) * 0x3F80u;
  return r;
}

// ---------------- K0: weights -> bf16 (stacked q,k,v), BN params fused ----------------
__global__ __launch_bounds__(256) void k_convert(
    const float* __restrict__ qw, const float* __restrict__ kw,
    const float* __restrict__ vw, const float* __restrict__ pw,
    const float* __restrict__ qg, const float* __restrict__ qbt,
    const float* __restrict__ qm, const float* __restrict__ qv,
    const float* __restrict__ kg, const float* __restrict__ kbt,
    const float* __restrict__ km, const float* __restrict__ kv,
    const float* __restrict__ vg, const float* __restrict__ vbt,
    const float* __restrict__ vm, const float* __restrict__ vv,
    const float* __restrict__ pg, const float* __restrict__ pbt,
    const float* __restrict__ pm, const float* __restrict__ pv,
    const float* __restrict__ pbias,
    u16* __restrict__ Wstk, u16* __restrict__ Pw,
    float4* __restrict__ BNP, float4* __restrict__ PP) {
  int tid = blockIdx.x * 256 + threadIdx.x;
  if (tid < 442368) {               // Wstk[1152][384]
    int r = tid / 384, c = tid - r * 384;
    const float* src = (r < 384) ? qw : (r < 768) ? kw : vw;
    int rr = (r >= 768) ? r - 768 : (r >= 384) ? r - 384 : r;
    unsigned int u = __float_as_uint(src[rr * 384 + c]);
    u = (u + 0x7FFFu + ((u >> 16) & 1u)) >> 16;   // RNE to bf16
    Wstk[tid] = (u16)u;
  } else if (tid < 589824) {        // Pw[384][384]
    int i = tid - 442368;
    unsigned int u = __float_as_uint(pw[i]);
    u = (u + 0x7FFFu + ((u >> 16) & 1u)) >> 16;
    Pw[i] = (u16)u;
  } else if (tid < 590976) {        // BNP[1152] = {inv, mean, beta, -}
    int r = tid - 589824;
    int br = r / 384, ch = r - br * 384;
    const float* g  = (br == 0) ? qg  : (br == 1) ? kg  : vg;
    const float* bt = (br == 0) ? qbt : (br == 1) ? kbt : vbt;
    const float* m  = (br == 0) ? qm  : (br == 1) ? km  : vm;
    const float* va = (br == 0) ? qv  : (br == 1) ? kv  : vv;
    float inv = g[ch] / sqrtf(va[ch] + 1e-5f);
    BNP[r] = make_float4(inv, m[ch], bt[ch], 0.f);
  } else if (tid < 591360) {        // PP[384] = {inv, mean, beta, bias}
    int ch = tid - 590976;
    float inv = pg[ch] / sqrtf(pv[ch] + 1e-5f);
    PP[ch] = make_float4(inv, pm[ch], pbt[ch], pbias[ch]);
  }
}

// ---------------- K1: input LIF -> packed nibble xsb[(b*1024+n)*384 + c] --------------
__global__ __launch_bounds__(256) void k_lif_in(const float* __restrict__ x, u8* __restrict__ xsb) {
  const int nt = blockIdx.x, ct = blockIdx.y, b = blockIdx.z;
  const int tid = threadIdx.x;
  const int nj = tid & 63, cr = tid >> 6;
  const int c0 = ct * 64, n0 = nt * 64;
  __shared__ u32 nibs[64 * 65];     // [nj][c], +1-pad (u32) -> conflict-free
  float v[16];
  u32 nib[16];
  #pragma unroll
  for (int i = 0; i < 16; ++i) { v[i] = 0.f; nib[i] = 0u; }
  for (int t = 0; t < 4; ++t) {
    const float* xr = x + (((t * 16 + b) * 384 + c0 + cr) * 1024) + n0 + nj;
    #pragma unroll
    for (int it = 0; it < 16; ++it) {
      float xv = xr[it * 4096];
      float vv = v[it];
      float h = __fadd_rn(vv, __fmul_rn(__fsub_rn(xv, vv), 0.5f));  // v + (x-v)/2, exact order
      bool s = h >= 1.f;
      v[it] = s ? 0.f : h;
      nib[it] |= (s ? 1u : 0u) << t;
    }
  }
  #pragma unroll
  for (int it = 0; it < 16; ++it) nibs[nj * 65 + cr + it * 4] = nib[it];
  __syncthreads();
  const int n = tid >> 2, ch = tid & 3;
  u32 w0[4];
  #pragma unroll
  for (int q = 0; q < 4; ++q) {
    u32 acc = 0;
    #pragma unroll
    for (int i = 0; i < 4; ++i)
      acc |= (nibs[n * 65 + ch * 16 + q * 4 + i] & 0xFu) << (8 * i);
    w0[q] = acc;
  }
  *(uint4*)(xsb + ((size_t)(b * 1024 + n0 + n)) * 384 + c0 + ch * 16) =
      make_uint4(w0[0], w0[1], w0[2], w0[3]);
}

// ======================================================================================
// GEMM core v7 (wide-c waves): 256 thr / 4 waves; wave = 64 j (16 n x 4 t) x 128 c.
// ji=4, ci=8 -> 32 MFMA per wave per K-tile; one A-expand feeds 8 MFMAs (2x v9).
// X packed-resident in LDS (26 KB, 416B rows), broadcast-read + expand per wave (v9).
// W pipeline: 3 x 8KB buffers, 2 gll16/thread/tile, 2 tiles in flight, vmcnt(2).
// Single-phase GSTEP (R10's 2-phase split measured -5%). acc[4][8]=128 regs; cap 256
// via __launch_bounds__(256,2) -> 2 blocks/CU (2 x 51200B LDS), independent barriers.
// W chunk XOR swizzle: slot cp holds logical chunk cp ^ ((row>>1)&3) (verified v2-v9).
// ======================================================================================
#define XLDS_U16 13312                 // 26624 B X region (64 rows x 416 B)
#define WSLOT_U16 4096                 // 8 KB per W buffer slot

#define GISSUE(kt) do { \
    u16* wb_ = &lds[XLDS_U16 + ((kt) % 3) * WSLOT_U16 + w * 1024]; \
    gll16(Wp0 + (kt) * 32, wb_); \
    gll16(Wp1 + (kt) * 32, wb_ + 512); \
  } while (0)

#define GSTEP(t, VN, ISS) do { \
    asm volatile("s_waitcnt vmcnt(" #VN ")" ::: "memory"); \
    __builtin_amdgcn_s_barrier(); \
    asm volatile("" ::: "memory"); \
    ISS; \
    const u8* xb_ = (const u8*)lds; \
    const u16* wb_ = &lds[XLDS_U16 + ((t) % 3) * WSLOT_U16]; \
    bf16x8 ax[4]; \
    _Pragma("unroll") \
    for (int ji = 0; ji < 4; ++ji) { \
      uint2 xr_ = *(const uint2*)(xb_ + (w * 16 + ji * 4 + d4) * 416 + (t) * 32 + g8); \
      uint4 e_ = expand8f(xr_, t_lane); \
      ax[ji] = *(bf16x8*)&e_; \
    } \
    __builtin_amdgcn_s_setprio(1); \
    _Pragma("unroll") \
    for (int ci = 0; ci < 8; ++ci) { \
      bf16x8 bw_ = *(const bf16x8*)&wb_[(ci * 16 + l15) * 32 + swoff]; \
      _Pragma("unroll") \
      for (int ji = 0; ji < 4; ++ji) \
        acc[ji][ci] = __builtin_amdgcn_mfma_f32_16x16x32_bf16(ax[ji], bw_, acc[ji][ci], 0, 0, 0); \
    } \
    __builtin_amdgcn_s_setprio(0); \
  } while (0)

#define GEMM_PIPELINE() do { \
    GISSUE(0); GISSUE(1); \
    GSTEP(0, 2, GISSUE(2)); \
    GSTEP(1, 2, GISSUE(3)); \
    GSTEP(2, 2, GISSUE(4)); \
    GSTEP(3, 2, GISSUE(5)); \
    GSTEP(4, 2, GISSUE(6)); \
    GSTEP(5, 2, GISSUE(7)); \
    GSTEP(6, 2, GISSUE(8)); \
    GSTEP(7, 2, GISSUE(9)); \
    GSTEP(8, 2, GISSUE(10)); \
    GSTEP(9, 2, GISSUE(11)); \
    GSTEP(10, 2, ); \
    GSTEP(11, 0, ); \
  } while (0)

// stage packed X strip (64 n x 384 B) into padded LDS rows (416 B), then sync
#define XSTAGE(XSRC) do { \
    const int xn_ = tid >> 2, xcp_ = tid & 3; \
    const u8* xs_ = (XSRC) + (size_t)(b * 1024 + jt * 64 + xn_) * 384 + xcp_ * 96; \
    u8* xd_ = (u8*)lds + xn_ * 416 + xcp_ * 96; \
    _Pragma("unroll") \
    for (int q_ = 0; q_ < 6; ++q_) \
      *(uint4*)(xd_ + q_ * 16) = *(const uint4*)(xs_ + q_ * 16); \
    __syncthreads(); \
  } while (0)

#define GEMM_SETUP() \
  const int tid = threadIdx.x; \
  const int w = tid >> 6, l = tid & 63; \
  const int l15 = tid & 15, g = l >> 4; \
  const int swoff = (g ^ ((l15 >> 1) & 3)) * 8; \
  const int d4 = l15 >> 2, g8 = g * 8; \
  const u32 t_lane = (u32)(l15 & 3); \
  const int sch = (l & 3) ^ ((l >> 3) & 3); \
  f32x4 acc[4][8]; \
  { const f32x4 zero_ = {0.f, 0.f, 0.f, 0.f}; \
    _Pragma("unroll") \
    for (int ji = 0; ji < 4; ++ji) \
      _Pragma("unroll") \
      for (int ci = 0; ci < 8; ++ci) acc[ji][ci] = zero_; }

// ---------------- K2: qkv GEMM (one branch-panel per block) + BN + LIF -> sp nibbles --
__global__ __launch_bounds__(256, 2) void k_qkv(
    const u16* __restrict__ Wstk, const u8* __restrict__ xsb,
    const float4* __restrict__ BNP, u8* __restrict__ sp) {
  const int jt = blockIdx.x, mt = blockIdx.y, b = blockIdx.z;
  __shared__ u16 lds[25600];                      // 26624B X + 3x8KB W = 51200 B

  GEMM_SETUP();
  XSTAGE(xsb);

  const int m0 = mt * 128;                        // == (mt/3)*384 + (mt%3)*128 in Wstk
  const u16* Wp0 = Wstk + (size_t)(m0 + w * 32 + (l >> 2)) * 384 + sch * 8;
  const u16* Wp1 = Wp0 + 16 * 384;

  GEMM_PIPELINE();

  // epilogue: BN + 4-step LIF (acc regs = t), pack 4 spike bits -> one u8
  const int br = mt / 3;
  const int cb = (mt - br * 3) * 128;
  const int n_base = b * 1024 + jt * 64 + w * 16 + g;
  u8* spW = sp + (size_t)br * SPB;
  #pragma unroll
  for (int ci = 0; ci < 8; ++ci) {
    const int c_loc = ci * 16 + l15;
    float4 pr = BNP[br * 384 + cb + c_loc];       // direct L2 load
    #pragma unroll
    for (int ji = 0; ji < 4; ++ji) {
      f32x4 a = acc[ji][ci];
      u32 bits = 0;
      float vv = 0.f;
      #pragma unroll
      for (int t = 0; t < 4; ++t) {
        float z = __fadd_rn(__fmul_rn(__fsub_rn(a[t], pr.y), pr.x), pr.z);  // BN, ref order
        float h = __fadd_rn(vv, __fmul_rn(__fsub_rn(z, vv), 0.5f));          // LIF step
        bool s = h >= 1.f;
        vv = s ? 0.f : h;
        bits |= (s ? 1u : 0u) << t;
      }
      spW[(size_t)(n_base + ji * 4) * 384 + cb + c_loc] = (u8)bits;
    }
  }
}

// ---------------- K3: attn = sum_ch(k&v) per head, LIF(0.5) -> xpb = q & mask ---------
__global__ __launch_bounds__(256) void k_attn(const u8* __restrict__ sp, u8* __restrict__ xpb) {
  const int gw = blockIdx.x * 4 + (threadIdx.x >> 6);
  const int l = threadIdx.x & 63;
  const int b = gw >> 10, n = gw & 1023;
  const u8* qB = sp;
  const u8* kB = sp + SPB;
  const u8* vB = sp + 2 * SPB;
  const int base = (b * 1024 + n) * 384 + l * 6;   // byte index; lane covers 6 channels
  u16 qu[3], ku[3], vu[3];
  #pragma unroll
  for (int i = 0; i < 3; ++i) {
    qu[i] = *(const u16*)(qB + base + 2 * i);
    ku[i] = *(const u16*)(kB + base + 2 * i);
    vu[i] = *(const u16*)(vB + base + 2 * i);
  }
  u32 s = 0;                        // 4 per-t byte sums packed in a u32
  #pragma unroll
  for (int i = 0; i < 3; ++i) {
    u32 a = (u32)(ku[i] & vu[i]);
    #pragma unroll
    for (int t = 0; t < 4; ++t) {
      u32 x = (a >> t) & 0x0101u;
      s += ((x + (x >> 8)) & 3u) << (8 * t);
    }
  }
  s += __shfl_xor(s, 1);
  s += __shfl_xor(s, 2);
  s += __shfl_xor(s, 4);            // 8 lanes == one 48-channel head; bytes <= 48
  float v = 0.f;
  u32 m8 = 0;
  #pragma unroll
  for (int t = 0; t < 4; ++t) {
    float attn = (float)((s >> (8 * t)) & 0xFFu);
    float h = __fadd_rn(v, __fmul_rn(__fsub_rn(attn, v), 0.5f));
    bool sk = h >= 0.5f;
    v = sk ? 0.f : h;
    m8 |= (sk ? 1u : 0u) << t;
  }
  const u16 mm = (u16)(m8 * 0x0101u);
  u16* dst = (u16*)(xpb + base);
  #pragma unroll
  for (int i = 0; i < 3; ++i) dst[i] = qu[i] & mm;
}

// ---------------- K4: P GEMM (one 128-c panel per block) + bias + BN -> out fp32 ------
__global__ __launch_bounds__(256, 2) void k_proj(
    const u16* __restrict__ Pw, const u8* __restrict__ xpb,
    const float4* __restrict__ PP, float* __restrict__ out) {
  const int jt = blockIdx.x, mt = blockIdx.y, b = blockIdx.z;
  __shared__ u16 lds[25600];

  GEMM_SETUP();
  XSTAGE(xpb);

  const int m0 = mt * 128;
  const u16* Wp0 = Pw + (size_t)(m0 + w * 32 + (l >> 2)) * 384 + sch * 8;
  const u16* Wp1 = Wp0 + 16 * 384;

  GEMM_PIPELINE();

  __syncthreads();                                 // all waves done with LDS buffers
  float* scr = (float*)lds;                        // 128 x 68-padded f32 tile (34.8 KB)
  const int n0im = jt * 64;
  float4 prc[8];
  #pragma unroll
  for (int ci = 0; ci < 8; ++ci) prc[ci] = PP[m0 + ci * 16 + l15];

  #pragma unroll
  for (int t = 0; t < 4; ++t) {
    #pragma unroll
    for (int ci = 0; ci < 8; ++ci) {
      const int c_loc = ci * 16 + l15;
      float4 pr = prc[ci];
      #pragma unroll
      for (int ji = 0; ji < 4; ++ji) {
        const int n_loc = w * 16 + ji * 4 + g;
        float zz = __fadd_rn(acc[ji][ci][t], pr.w);                        // + bias
        zz = __fadd_rn(__fmul_rn(__fsub_rn(zz, pr.y), pr.x), pr.z);        // BN, ref order
        scr[c_loc * 68 + n_loc] = zz;
      }
    }
    __syncthreads();
    #pragma unroll
    for (int it = 0; it < 8; ++it) {
      int slot = tid + it * 256;                   // 2048 slots = 128 rows x 16 float4
      int c = slot >> 4, li = slot & 15;
      float4 val = *(const float4*)&scr[c * 68 + li * 4];
      *(float4*)&out[(((size_t)(t * 16 + b) * 384) + m0 + c) * 1024 + n0im + li * 4] = val;
    }
    __syncthreads();
  }
}

extern "C" void kernel_launch(void* const* d_in, const int* in_sizes, int n_in,
                              void* d_out, int out_size, void* d_ws, size_t ws_size,
                              hipStream_t stream) {
  (void)in_sizes; (void)n_in; (void)out_size; (void)ws_size;
  const float* x   = (const float*)d_in[0];
  const float* qw  = (const float*)d_in[1];
  const float* qg  = (const float*)d_in[2];
  const float* qbt = (const float*)d_in[3];
  const float* qm  = (const float*)d_in[4];
  const float* qv  = (const float*)d_in[5];
  const float* kw  = (const float*)d_in[6];
  const float* kg  = (const float*)d_in[7];
  const float* kbt = (const float*)d_in[8];
  const float* km  = (const float*)d_in[9];
  const float* kv  = (const float*)d_in[10];
  const float* vw  = (const float*)d_in[11];
  const float* vg  = (const float*)d_in[12];
  const float* vbt = (const float*)d_in[13];
  const float* vm  = (const float*)d_in[14];
  const float* vv  = (const float*)d_in[15];
  const float* pw  = (const float*)d_in[16];
  const float* pg  = (const float*)d_in[17];
  const float* pbt = (const float*)d_in[18];
  const float* pm  = (const float*)d_in[19];
  const float* pv  = (const float*)d_in[20];
  const float* pbias = (const float*)d_in[21];

  char* ws = (char*)d_ws;
  u8*  xsb   = (u8*)ws;                     // input spikes, packed nibbles (6.3 MB)
  u8*  sp    = (u8*)(ws + 6291456);         // q,k,v spike nibbles (3 x 6.3 MB)
  u8*  xpb   = (u8*)(ws + 25165824);        // q&attn spikes, packed nibbles (6.3 MB)
  u16* Wstk  = (u16*)(ws + 31457280);       // [1152][384] bf16
  u16* Pw    = (u16*)(ws + 32342016);       // [384][384] bf16
  float4* BNP = (float4*)(ws + 32636928);   // [1152]
  float4* PP  = (float4*)(ws + 32655360);   // [384]

  k_convert<<<2310, 256, 0, stream>>>(qw, kw, vw, pw, qg, qbt, qm, qv, kg, kbt, km, kv,
                                      vg, vbt, vm, vv, pg, pbt, pm, pv, pbias,
                                      Wstk, Pw, BNP, PP);
  k_lif_in<<<dim3(16, 6, 16), 256, 0, stream>>>(x, xsb);
  k_qkv<<<dim3(16, 9, 16), 256, 0, stream>>>(Wstk, xsb, BNP, sp);
  k_attn<<<4096, 256, 0, stream>>>(sp, xpb);
  k_proj<<<dim3(16, 3, 16), 256, 0, stream>>>(Pw, xpb, PP, (float*)d_out);
}

// Round 12
// 119.047 us; speedup vs baseline: 1.0829x; 1.0807x over previous
//
#include <hip/hip_runtime.h>

typedef unsigned short u16;
typedef unsigned char u8;
typedef unsigned int u32;
typedef float f32x4 __attribute__((ext_vector_type(4)));
typedef __bf16 bf16x8 __attribute__((ext_vector_type(8)));

#define SPB 6291456      // bytes per packed branch: B*N*C = 16*1024*384 (u8, 4 t-bits)

// ---- async global->LDS, 16B per lane, dest = wave-uniform base + lane*16 ----
__device__ __forceinline__ void gll16(const void* g, void* l) {
  __builtin_amdgcn_global_load_lds((const __attribute__((address_space(1))) void*)g,
                                   (__attribute__((address_space(3))) void*)l, 16, 0, 0);
}

// expand 8 packed spike-bytes (bit t) -> 8 bf16 {0,1}; perm+mul: (b0|b1<<16)*0x3F80
__device__ __forceinline__ uint4 expand8f(uint2 v, u32 t) {
  u32 a = (v.x >> t) & 0x01010101u;
  u32 b = (v.y >> t) & 0x01010101u;
  uint4 r;
  r.x = __builtin_amdgcn_perm(0u, a, 0x0C010C00u) * 0x3F80u;
  r.y = __builtin_amdgcn_perm(0u, a, 0x0C030C02u) * 0x3F80u;
  r.z = __builtin_amdgcn_perm(0u, b, 0x0C010C00u) * 0x3F80u;
  r.w = __builtin_amdgcn_perm(0u, b, 0x0C030C02u) * 0x3F80u;
  return r;
}

// ---------------- K0: weights -> bf16 (stacked q,k,v), BN params fused ----------------
__global__ __launch_bounds__(256) void k_convert(
    const float* __restrict__ qw, const float* __restrict__ kw,
    const float* __restrict__ vw, const float* __restrict__ pw,
    const float* __restrict__ qg, const float* __restrict__ qbt,
    const float* __restrict__ qm, const float* __restrict__ qv,
    const float* __restrict__ kg, const float* __restrict__ kbt,
    const float* __restrict__ km, const float* __restrict__ kv,
    const float* __restrict__ vg, const float* __restrict__ vbt,
    const float* __restrict__ vm, const float* __restrict__ vv,
    const float* __restrict__ pg, const float* __restrict__ pbt,
    const float* __restrict__ pm, const float* __restrict__ pv,
    const float* __restrict__ pbias,
    u16* __restrict__ Wstk, u16* __restrict__ Pw,
    float4* __restrict__ BNP, float4* __restrict__ PP) {
  int tid = blockIdx.x * 256 + threadIdx.x;
  if (tid < 442368) {               // Wstk[1152][384]
    int r = tid / 384, c = tid - r * 384;
    const float* src = (r < 384) ? qw : (r < 768) ? kw : vw;
    int rr = (r >= 768) ? r - 768 : (r >= 384) ? r - 384 : r;
    unsigned int u = __float_as_uint(src[rr * 384 + c]);
    u = (u + 0x7FFFu + ((u >> 16) & 1u)) >> 16;   // RNE to bf16
    Wstk[tid] = (u16)u;
  } else if (tid < 589824) {        // Pw[384][384]
    int i = tid - 442368;
    unsigned int u = __float_as_uint(pw[i]);
    u = (u + 0x7FFFu + ((u >> 16) & 1u)) >> 16;
    Pw[i] = (u16)u;
  } else if (tid < 590976) {        // BNP[1152] = {inv, mean, beta, -}
    int r = tid - 589824;
    int br = r / 384, ch = r - br * 384;
    const float* g  = (br == 0) ? qg  : (br == 1) ? kg  : vg;
    const float* bt = (br == 0) ? qbt : (br == 1) ? kbt : vbt;
    const float* m  = (br == 0) ? qm  : (br == 1) ? km  : vm;
    const float* va = (br == 0) ? qv  : (br == 1) ? kv  : vv;
    float inv = g[ch] / sqrtf(va[ch] + 1e-5f);
    BNP[r] = make_float4(inv, m[ch], bt[ch], 0.f);
  } else if (tid < 591360) {        // PP[384] = {inv, mean, beta, bias}
    int ch = tid - 590976;
    float inv = pg[ch] / sqrtf(pv[ch] + 1e-5f);
    PP[ch] = make_float4(inv, pm[ch], pbt[ch], pbias[ch]);
  }
}

// ---------------- K1: input LIF -> packed nibble xsb[(b*1024+n)*384 + c] --------------
// float4 reads along n (4x fewer load instrs than scalar); phase-2 transpose unchanged.
__global__ __launch_bounds__(256) void k_lif_in(const float* __restrict__ x, u8* __restrict__ xsb) {
  const int nt = blockIdx.x, ct = blockIdx.y, b = blockIdx.z;
  const int tid = threadIdx.x;
  const int n4 = tid & 15, cL = tid >> 4;     // 16 n-quads x 16 c-lanes
  const int c0 = ct * 64, n0 = nt * 64;
  __shared__ u32 nibs[64 * 65];               // [n][c], 65-pad -> 2-way max on writes
  float v[4][4];
  u32 nib[4][4];
  #pragma unroll
  for (int it = 0; it < 4; ++it)
    #pragma unroll
    for (int ns = 0; ns < 4; ++ns) { v[it][ns] = 0.f; nib[it][ns] = 0u; }
  for (int t = 0; t < 4; ++t) {
    #pragma unroll
    for (int it = 0; it < 4; ++it) {
      const float4 xv = *(const float4*)&x[(size_t)(((t * 16 + b) * 384 + c0 + cL + it * 16)) * 1024
                                           + n0 + n4 * 4];
      #pragma unroll
      for (int ns = 0; ns < 4; ++ns) {
        float xe = (ns == 0) ? xv.x : (ns == 1) ? xv.y : (ns == 2) ? xv.z : xv.w;
        float vv = v[it][ns];
        float h = __fadd_rn(vv, __fmul_rn(__fsub_rn(xe, vv), 0.5f));  // v + (x-v)/2, exact order
        bool s = h >= 1.f;
        v[it][ns] = s ? 0.f : h;
        nib[it][ns] |= (s ? 1u : 0u) << t;
      }
    }
  }
  #pragma unroll
  for (int it = 0; it < 4; ++it)
    #pragma unroll
    for (int ns = 0; ns < 4; ++ns)
      nibs[(n4 * 4 + ns) * 65 + cL + it * 16] = nib[it][ns];
  __syncthreads();
  const int n = tid >> 2, ch = tid & 3;
  u32 w0[4];
  #pragma unroll
  for (int q = 0; q < 4; ++q) {
    u32 acc = 0;
    #pragma unroll
    for (int i = 0; i < 4; ++i)
      acc |= (nibs[n * 65 + ch * 16 + q * 4 + i] & 0xFu) << (8 * i);
    w0[q] = acc;
  }
  *(uint4*)(xsb + ((size_t)(b * 1024 + n0 + n)) * 384 + c0 + ch * 16) =
      make_uint4(w0[0], w0[1], w0[2], w0[3]);
}

// ======================================================================================
// GEMM core v5 (R9, measured 70.8us k_qkv): BM=128 c, BN=256 j (64 n x 4 t), K=384 full.
// X packed-resident in LDS (26 KB, 416B-padded rows), expanded to bf16 on read.
// W pipelined: 6 x 8KB buffers, 1 gll16/thread/tile, 5 tiles in flight, vmcnt(4).
// LDS 75776 B -> 2 blocks/CU, 4 waves/SIMD. 0 bank conflicts (verified).
// ======================================================================================
#define XLDS_U16 13312                 // 26624 B X region (64 rows x 416 B)
#define WSLOT_U16 4096                 // 8 KB per W buffer slot

#define GISSUE(kt) gll16(Wp + (kt) * 32, &lds[XLDS_U16 + ((kt) % 6) * WSLOT_U16 + wst])

#define SYNCP(n) do { \
    asm volatile("s_waitcnt vmcnt(" #n ")" ::: "memory"); \
    __builtin_amdgcn_s_barrier(); \
    asm volatile("" ::: "memory"); \
  } while (0)

#define COMPUTE(kt) do { \
    const u8* xb_ = (const u8*)lds; \
    const u16* wb_ = &lds[XLDS_U16 + ((kt) % 6) * WSLOT_U16]; \
    bf16x8 ax[4]; \
    _Pragma("unroll") \
    for (int ji = 0; ji < 4; ++ji) { \
      uint2 xr_ = *(const uint2*)(xb_ + (wjg * 16 + ji * 4 + d4) * 416 + (kt) * 32 + g8); \
      uint4 e_ = expand8f(xr_, t_lane); \
      ax[ji] = *(bf16x8*)&e_; \
    } \
    __builtin_amdgcn_s_setprio(1); \
    _Pragma("unroll") \
    for (int ci = 0; ci < 4; ++ci) { \
      bf16x8 bw_ = *(const bf16x8*)&wb_[(wcg * 64 + ci * 16 + l15) * 32 + swoff]; \
      _Pragma("unroll") \
      for (int ji = 0; ji < 4; ++ji) \
        acc[ji][ci] = __builtin_amdgcn_mfma_f32_16x16x32_bf16(ax[ji], bw_, acc[ji][ci], 0, 0, 0); \
    } \
    __builtin_amdgcn_s_setprio(0); \
  } while (0)

#define GEMM_PIPELINE() do { \
    GISSUE(0); GISSUE(1); GISSUE(2); GISSUE(3); GISSUE(4); \
    SYNCP(4); GISSUE(5);  COMPUTE(0); \
    SYNCP(4); GISSUE(6);  COMPUTE(1); \
    SYNCP(4); GISSUE(7);  COMPUTE(2); \
    SYNCP(4); GISSUE(8);  COMPUTE(3); \
    SYNCP(4); GISSUE(9);  COMPUTE(4); \
    SYNCP(4); GISSUE(10); COMPUTE(5); \
    SYNCP(4); GISSUE(11); COMPUTE(6); \
    SYNCP(4); COMPUTE(7); \
    SYNCP(3); COMPUTE(8); \
    SYNCP(2); COMPUTE(9); \
    SYNCP(1); COMPUTE(10); \
    SYNCP(0); COMPUTE(11); \
  } while (0)

// stage packed X strip (64 n x 384 B) into padded LDS rows (416 B), then sync
#define XSTAGE(XSRC) do { \
    const int xn_ = tid >> 3, xcp_ = tid & 7; \
    const u8* xs_ = (XSRC) + (size_t)(b * 1024 + jt * 64 + xn_) * 384 + xcp_ * 48; \
    u8* xd_ = (u8*)lds + xn_ * 416 + xcp_ * 48; \
    uint4 v0_ = *(const uint4*)(xs_); \
    uint4 v1_ = *(const uint4*)(xs_ + 16); \
    uint4 v2_ = *(const uint4*)(xs_ + 32); \
    *(uint4*)(xd_) = v0_; *(uint4*)(xd_ + 16) = v1_; *(uint4*)(xd_ + 32) = v2_; \
    __syncthreads(); \
  } while (0)

#define GEMM_SETUP() \
  const int tid = threadIdx.x; \
  const int w = tid >> 6, l = tid & 63; \
  const int wjg = w >> 1, wcg = w & 1; \
  const int l15 = tid & 15, g = l >> 4; \
  const int swoff = (g ^ ((l15 >> 1) & 3)) * 8; \
  const int wst = w * 512; \
  const int d4 = l15 >> 2, g8 = g * 8; \
  const u32 t_lane = (u32)(l15 & 3); \
  const int sch = (l & 3) ^ ((l >> 3) & 3); \
  f32x4 acc[4][4]; \
  { const f32x4 zero_ = {0.f, 0.f, 0.f, 0.f}; \
    _Pragma("unroll") \
    for (int ji = 0; ji < 4; ++ji) \
      _Pragma("unroll") \
      for (int ci = 0; ci < 4; ++ci) acc[ji][ci] = zero_; }

// ---------------- K2: qkv GEMM (one branch-panel per block) + BN + LIF -> sp nibbles --
__global__ __launch_bounds__(512, 4) void k_qkv(
    const u16* __restrict__ Wstk, const u8* __restrict__ xsb,
    const float4* __restrict__ BNP, u8* __restrict__ sp) {
  const int jt = blockIdx.x, mt = blockIdx.y, b = blockIdx.z;
  __shared__ u16 lds[37888];                      // 26624B X + 6x8KB W = 75776 B

  GEMM_SETUP();
  XSTAGE(xsb);

  const int m0 = mt * 128;                        // == (mt/3)*384 + (mt%3)*128 in Wstk
  const u16* Wp = Wstk + (size_t)(m0 + w * 16 + (l >> 2)) * 384 + sch * 8;

  GEMM_PIPELINE();

  // epilogue: BN + 4-step LIF (acc regs = t), pack 4 spike bits -> one u8
  const int br = mt / 3;
  const int cb = (mt - br * 3) * 128;
  const int n_base = b * 1024 + jt * 64 + wjg * 16 + g;
  u8* spW = sp + (size_t)br * SPB;
  #pragma unroll
  for (int ci = 0; ci < 4; ++ci) {
    const int c_loc = wcg * 64 + ci * 16 + l15;
    float4 pr = BNP[br * 384 + cb + c_loc];       // direct L2 load
    #pragma unroll
    for (int ji = 0; ji < 4; ++ji) {
      f32x4 a = acc[ji][ci];
      u32 bits = 0;
      float vv = 0.f;
      #pragma unroll
      for (int t = 0; t < 4; ++t) {
        float z = __fadd_rn(__fmul_rn(__fsub_rn(a[t], pr.y), pr.x), pr.z);  // BN, ref order
        float h = __fadd_rn(vv, __fmul_rn(__fsub_rn(z, vv), 0.5f));          // LIF step
        bool s = h >= 1.f;
        vv = s ? 0.f : h;
        bits |= (s ? 1u : 0u) << t;
      }
      spW[(size_t)(n_base + ji * 4) * 384 + cb + c_loc] = (u8)bits;
    }
  }
}

// ---------------- K4: P GEMM + FUSED attn (k&v head-sum, LIF(0.5), q-mask) ------------
// Stage thread-map (row=tid>>3, chunk=tid&7): one 48-B chunk == one head, so the attn
// reduction + LIF scan + q-mask are fully thread-local (integer fp32 -> bit-exact).
__global__ __launch_bounds__(512, 4) void k_proj(
    const u16* __restrict__ Pw, const u8* __restrict__ sp,
    const float4* __restrict__ PP, float* __restrict__ out) {
  const int jt = blockIdx.x, mt = blockIdx.y, b = blockIdx.z;
  __shared__ u16 lds[37888];

  {                                                // fused attn + X stage
    const int tt = threadIdx.x;
    const int xn_ = tt >> 3, hd_ = tt & 7;
    const u8* qrow = sp + (size_t)(b * 1024 + jt * 64 + xn_) * 384 + hd_ * 48;
    const u8* krow = qrow + SPB;
    const u8* vrow = qrow + 2 * SPB;
    u32 qa[12], ka[12], va[12];
    #pragma unroll
    for (int i = 0; i < 3; ++i) {
      *(uint4*)&qa[i * 4] = *(const uint4*)(qrow + i * 16);
      *(uint4*)&ka[i * 4] = *(const uint4*)(krow + i * 16);
      *(uint4*)&va[i * 4] = *(const uint4*)(vrow + i * 16);
    }
    u32 m0 = 0, m1 = 0, m2 = 0, m3 = 0;
    #pragma unroll
    for (int i = 0; i < 12; ++i) {
      u32 a = ka[i] & va[i];
      m0 += a & 0x01010101u;
      m1 += (a >> 1) & 0x01010101u;
      m2 += (a >> 2) & 0x01010101u;
      m3 += (a >> 3) & 0x01010101u;
    }
    float s0 = (float)((m0 * 0x01010101u) >> 24);  // head sums per t, <= 48, exact
    float s1 = (float)((m1 * 0x01010101u) >> 24);
    float s2 = (float)((m2 * 0x01010101u) >> 24);
    float s3 = (float)((m3 * 0x01010101u) >> 24);
    float vv = 0.f;
    u32 m8 = 0;
    #pragma unroll
    for (int t = 0; t < 4; ++t) {
      float attn = (t == 0) ? s0 : (t == 1) ? s1 : (t == 2) ? s2 : s3;
      float h = __fadd_rn(vv, __fmul_rn(__fsub_rn(attn, vv), 0.5f));
      bool sk = h >= 0.5f;
      vv = sk ? 0.f : h;
      m8 |= (sk ? 1u : 0u) << t;
    }
    const u32 mm = m8 * 0x01010101u;
    u8* xd_ = (u8*)lds + xn_ * 416 + hd_ * 48;
    #pragma unroll
    for (int i = 0; i < 3; ++i) {
      uint4 wv;
      wv.x = qa[i * 4 + 0] & mm;
      wv.y = qa[i * 4 + 1] & mm;
      wv.z = qa[i * 4 + 2] & mm;
      wv.w = qa[i * 4 + 3] & mm;
      *(uint4*)(xd_ + i * 16) = wv;
    }
    __syncthreads();
  }

  GEMM_SETUP();

  const int m0 = mt * 128;
  const u16* Wp = Pw + (size_t)(m0 + w * 16 + (l >> 2)) * 384 + sch * 8;

  GEMM_PIPELINE();

  __syncthreads();                                 // all waves done with LDS buffers
  float* scr = (float*)lds;                        // 128 x 68-padded f32 tile (34.8 KB)
  const int n0im = jt * 64;
  float4 prc[4];
  #pragma unroll
  for (int ci = 0; ci < 4; ++ci) prc[ci] = PP[m0 + wcg * 64 + ci * 16 + l15];

  #pragma unroll
  for (int t = 0; t < 4; ++t) {
    #pragma unroll
    for (int ci = 0; ci < 4; ++ci) {
      const int c_loc = wcg * 64 + ci * 16 + l15;
      float4 pr = prc[ci];
      #pragma unroll
      for (int ji = 0; ji < 4; ++ji) {
        const int n_loc = wjg * 16 + ji * 4 + g;
        float zz = __fadd_rn(acc[ji][ci][t], pr.w);                        // + bias
        zz = __fadd_rn(__fmul_rn(__fsub_rn(zz, pr.y), pr.x), pr.z);        // BN, ref order
        scr[c_loc * 68 + n_loc] = zz;
      }
    }
    __syncthreads();
    #pragma unroll
    for (int it = 0; it < 4; ++it) {
      int slot = tid + it * 512;                   // 2048 slots = 128 rows x 16 float4
      int c = slot >> 4, li = slot & 15;
      float4 val = *(const float4*)&scr[c * 68 + li * 4];
      *(float4*)&out[(((size_t)(t * 16 + b) * 384) + m0 + c) * 1024 + n0im + li * 4] = val;
    }
    __syncthreads();
  }
}

extern "C" void kernel_launch(void* const* d_in, const int* in_sizes, int n_in,
                              void* d_out, int out_size, void* d_ws, size_t ws_size,
                              hipStream_t stream) {
  (void)in_sizes; (void)n_in; (void)out_size; (void)ws_size;
  const float* x   = (const float*)d_in[0];
  const float* qw  = (const float*)d_in[1];
  const float* qg  = (const float*)d_in[2];
  const float* qbt = (const float*)d_in[3];
  const float* qm  = (const float*)d_in[4];
  const float* qv  = (const float*)d_in[5];
  const float* kw  = (const float*)d_in[6];
  const float* kg  = (const float*)d_in[7];
  const float* kbt = (const float*)d_in[8];
  const float* km  = (const float*)d_in[9];
  const float* kv  = (const float*)d_in[10];
  const float* vw  = (const float*)d_in[11];
  const float* vg  = (const float*)d_in[12];
  const float* vbt = (const float*)d_in[13];
  const float* vm  = (const float*)d_in[14];
  const float* vv  = (const float*)d_in[15];
  const float* pw  = (const float*)d_in[16];
  const float* pg  = (const float*)d_in[17];
  const float* pbt = (const float*)d_in[18];
  const float* pm  = (const float*)d_in[19];
  const float* pv  = (const float*)d_in[20];
  const float* pbias = (const float*)d_in[21];

  char* ws = (char*)d_ws;
  u8*  xsb   = (u8*)ws;                     // input spikes, packed nibbles (6.3 MB)
  u8*  sp    = (u8*)(ws + 6291456);         // q,k,v spike nibbles (3 x 6.3 MB)
  u16* Wstk  = (u16*)(ws + 31457280);       // [1152][384] bf16
  u16* Pw    = (u16*)(ws + 32342016);       // [384][384] bf16
  float4* BNP = (float4*)(ws + 32636928);   // [1152]
  float4* PP  = (float4*)(ws + 32655360);   // [384]

  k_convert<<<2310, 256, 0, stream>>>(qw, kw, vw, pw, qg, qbt, qm, qv, kg, kbt, km, kv,
                                      vg, vbt, vm, vv, pg, pbt, pm, pv, pbias,
                                      Wstk, Pw, BNP, PP);
  k_lif_in<<<dim3(16, 6, 16), 256, 0, stream>>>(x, xsb);
  k_qkv<<<dim3(16, 9, 16), 512, 0, stream>>>(Wstk, xsb, BNP, sp);
  k_proj<<<dim3(16, 3, 16), 512, 0, stream>>>(Pw, sp, PP, (float*)d_out);
}

// Round 13
// 116.113 us; speedup vs baseline: 1.1103x; 1.0253x over previous
//
#include <hip/hip_runtime.h>

typedef unsigned short u16;
typedef unsigned char u8;
typedef unsigned int u32;
typedef float f32x4 __attribute__((ext_vector_type(4)));
typedef __bf16 bf16x8 __attribute__((ext_vector_type(8)));

#define SPB 6291456      // bytes per packed branch: B*N*C = 16*1024*384 (u8, 4 t-bits)

// ---- async global->LDS, 16B per lane, dest = wave-uniform base + lane*16 ----
__device__ __forceinline__ void gll16(const void* g, void* l) {
  __builtin_amdgcn_global_load_lds((const __attribute__((address_space(1))) void*)g,
                                   (__attribute__((address_space(3))) void*)l, 16, 0, 0);
}

// expand 8 packed spike-bytes (bit t) -> 8 bf16 {0,1}; perm+mul: (b0|b1<<16)*0x3F80
__device__ __forceinline__ uint4 expand8f(uint2 v, u32 t) {
  u32 a = (v.x >> t) & 0x01010101u;
  u32 b = (v.y >> t) & 0x01010101u;
  uint4 r;
  r.x = __builtin_amdgcn_perm(0u, a, 0x0C010C00u) * 0x3F80u;
  r.y = __builtin_amdgcn_perm(0u, a, 0x0C030C02u) * 0x3F80u;
  r.z = __builtin_amdgcn_perm(0u, b, 0x0C010C00u) * 0x3F80u;
  r.w = __builtin_amdgcn_perm(0u, b, 0x0C030C02u) * 0x3F80u;
  return r;
}

// ---------------- K0: weights -> bf16 (stacked q,k,v), BN params fused ----------------
__global__ __launch_bounds__(256) void k_convert(
    const float* __restrict__ qw, const float* __restrict__ kw,
    const float* __restrict__ vw, const float* __restrict__ pw,
    const float* __restrict__ qg, const float* __restrict__ qbt,
    const float* __restrict__ qm, const float* __restrict__ qv,
    const float* __restrict__ kg, const float* __restrict__ kbt,
    const float* __restrict__ km, const float* __restrict__ kv,
    const float* __restrict__ vg, const float* __restrict__ vbt,
    const float* __restrict__ vm, const float* __restrict__ vv,
    const float* __restrict__ pg, const float* __restrict__ pbt,
    const float* __restrict__ pm, const float* __restrict__ pv,
    const float* __restrict__ pbias,
    u16* __restrict__ Wstk, u16* __restrict__ Pw,
    float4* __restrict__ BNP, float4* __restrict__ PP) {
  int tid = blockIdx.x * 256 + threadIdx.x;
  if (tid < 442368) {               // Wstk[1152][384]
    int r = tid / 384, c = tid - r * 384;
    const float* src = (r < 384) ? qw : (r < 768) ? kw : vw;
    int rr = (r >= 768) ? r - 768 : (r >= 384) ? r - 384 : r;
    unsigned int u = __float_as_uint(src[rr * 384 + c]);
    u = (u + 0x7FFFu + ((u >> 16) & 1u)) >> 16;   // RNE to bf16
    Wstk[tid] = (u16)u;
  } else if (tid < 589824) {        // Pw[384][384]
    int i = tid - 442368;
    unsigned int u = __float_as_uint(pw[i]);
    u = (u + 0x7FFFu + ((u >> 16) & 1u)) >> 16;
    Pw[i] = (u16)u;
  } else if (tid < 590976) {        // BNP[1152] = {inv, mean, beta, -}
    int r = tid - 589824;
    int br = r / 384, ch = r - br * 384;
    const float* g  = (br == 0) ? qg  : (br == 1) ? kg  : vg;
    const float* bt = (br == 0) ? qbt : (br == 1) ? kbt : vbt;
    const float* m  = (br == 0) ? qm  : (br == 1) ? km  : vm;
    const float* va = (br == 0) ? qv  : (br == 1) ? kv  : vv;
    float inv = g[ch] / sqrtf(va[ch] + 1e-5f);
    BNP[r] = make_float4(inv, m[ch], bt[ch], 0.f);
  } else if (tid < 591360) {        // PP[384] = {inv, mean, beta, bias}
    int ch = tid - 590976;
    float inv = pg[ch] / sqrtf(pv[ch] + 1e-5f);
    PP[ch] = make_float4(inv, pm[ch], pbt[ch], pbias[ch]);
  }
}

// ---------------- K1: input LIF -> packed nibble xsb[(b*1024+n)*384 + c] --------------
// float4 reads along n (4x fewer load instrs than scalar); phase-2 transpose unchanged.
__global__ __launch_bounds__(256) void k_lif_in(const float* __restrict__ x, u8* __restrict__ xsb) {
  const int nt = blockIdx.x, ct = blockIdx.y, b = blockIdx.z;
  const int tid = threadIdx.x;
  const int n4 = tid & 15, cL = tid >> 4;     // 16 n-quads x 16 c-lanes
  const int c0 = ct * 64, n0 = nt * 64;
  __shared__ u32 nibs[64 * 65];               // [n][c], 65-pad -> 2-way max on writes
  float v[4][4];
  u32 nib[4][4];
  #pragma unroll
  for (int it = 0; it < 4; ++it)
    #pragma unroll
    for (int ns = 0; ns < 4; ++ns) { v[it][ns] = 0.f; nib[it][ns] = 0u; }
  for (int t = 0; t < 4; ++t) {
    #pragma unroll
    for (int it = 0; it < 4; ++it) {
      const float4 xv = *(const float4*)&x[(size_t)(((t * 16 + b) * 384 + c0 + cL + it * 16)) * 1024
                                           + n0 + n4 * 4];
      #pragma unroll
      for (int ns = 0; ns < 4; ++ns) {
        float xe = (ns == 0) ? xv.x : (ns == 1) ? xv.y : (ns == 2) ? xv.z : xv.w;
        float vv = v[it][ns];
        float h = __fadd_rn(vv, __fmul_rn(__fsub_rn(xe, vv), 0.5f));  // v + (x-v)/2, exact order
        bool s = h >= 1.f;
        v[it][ns] = s ? 0.f : h;
        nib[it][ns] |= (s ? 1u : 0u) << t;
      }
    }
  }
  #pragma unroll
  for (int it = 0; it < 4; ++it)
    #pragma unroll
    for (int ns = 0; ns < 4; ++ns)
      nibs[(n4 * 4 + ns) * 65 + cL + it * 16] = nib[it][ns];
  __syncthreads();
  const int n = tid >> 2, ch = tid & 3;
  u32 w0[4];
  #pragma unroll
  for (int q = 0; q < 4; ++q) {
    u32 acc = 0;
    #pragma unroll
    for (int i = 0; i < 4; ++i)
      acc |= (nibs[n * 65 + ch * 16 + q * 4 + i] & 0xFu) << (8 * i);
    w0[q] = acc;
  }
  *(uint4*)(xsb + ((size_t)(b * 1024 + n0 + n)) * 384 + c0 + ch * 16) =
      make_uint4(w0[0], w0[1], w0[2], w0[3]);
}

// ======================================================================================
// GEMM core v8 (paired barriers): BM=128 c, BN=256 j (64 n x 4 t), K=384 full.
// X packed-resident in LDS (26 KB, 416B-padded rows), expanded to bf16 on read (v5).
// W pipelined: 6 x 8KB ring, 1 gll16/thread/tile, 4 tiles in flight, vmcnt(2).
// TWO K-tiles per barrier interval (6 barriers vs v5's 12): inside a pair the compiler
// floats tile-2i+1's ds_reads/expand under tile-2i's MFMA burst (lgkmcnt scheduling).
// Ring hazards: pair i writes slot (2i+4)%6; reads (2i)%6,(2i+1)%6 (distinct); slot
// (2i+4)%6 last read in pair i-1 -> 1 barrier separation. LDS 75776 B -> 2 blocks/CU.
// ======================================================================================
#define XLDS_U16 13312                 // 26624 B X region (64 rows x 416 B)
#define WSLOT_U16 4096                 // 8 KB per W buffer slot

#define GISSUE(kt) gll16(Wp + (kt) * 32, &lds[XLDS_U16 + ((kt) % 6) * WSLOT_U16 + wst])

#define SYNCP(n) do { \
    asm volatile("s_waitcnt vmcnt(" #n ")" ::: "memory"); \
    __builtin_amdgcn_s_barrier(); \
    asm volatile("" ::: "memory"); \
  } while (0)

#define COMPUTE(kt) do { \
    const u8* xb_ = (const u8*)lds; \
    const u16* wb_ = &lds[XLDS_U16 + ((kt) % 6) * WSLOT_U16]; \
    bf16x8 ax[4]; \
    _Pragma("unroll") \
    for (int ji = 0; ji < 4; ++ji) { \
      uint2 xr_ = *(const uint2*)(xb_ + (wjg * 16 + ji * 4 + d4) * 416 + (kt) * 32 + g8); \
      uint4 e_ = expand8f(xr_, t_lane); \
      ax[ji] = *(bf16x8*)&e_; \
    } \
    __builtin_amdgcn_s_setprio(1); \
    _Pragma("unroll") \
    for (int ci = 0; ci < 4; ++ci) { \
      bf16x8 bw_ = *(const bf16x8*)&wb_[(wcg * 64 + ci * 16 + l15) * 32 + swoff]; \
      _Pragma("unroll") \
      for (int ji = 0; ji < 4; ++ji) \
        acc[ji][ci] = __builtin_amdgcn_mfma_f32_16x16x32_bf16(ax[ji], bw_, acc[ji][ci], 0, 0, 0); \
    } \
    __builtin_amdgcn_s_setprio(0); \
  } while (0)

#define GEMM_PIPELINE() do { \
    GISSUE(0); GISSUE(1); GISSUE(2); GISSUE(3); \
    SYNCP(2); GISSUE(4);  GISSUE(5);  COMPUTE(0);  COMPUTE(1); \
    SYNCP(2); GISSUE(6);  GISSUE(7);  COMPUTE(2);  COMPUTE(3); \
    SYNCP(2); GISSUE(8);  GISSUE(9);  COMPUTE(4);  COMPUTE(5); \
    SYNCP(2); GISSUE(10); GISSUE(11); COMPUTE(6);  COMPUTE(7); \
    SYNCP(2); COMPUTE(8);  COMPUTE(9); \
    SYNCP(0); COMPUTE(10); COMPUTE(11); \
  } while (0)

// stage packed X strip (64 n x 384 B) into padded LDS rows (416 B), then sync
#define XSTAGE(XSRC) do { \
    const int xn_ = tid >> 3, xcp_ = tid & 7; \
    const u8* xs_ = (XSRC) + (size_t)(b * 1024 + jt * 64 + xn_) * 384 + xcp_ * 48; \
    u8* xd_ = (u8*)lds + xn_ * 416 + xcp_ * 48; \
    uint4 v0_ = *(const uint4*)(xs_); \
    uint4 v1_ = *(const uint4*)(xs_ + 16); \
    uint4 v2_ = *(const uint4*)(xs_ + 32); \
    *(uint4*)(xd_) = v0_; *(uint4*)(xd_ + 16) = v1_; *(uint4*)(xd_ + 32) = v2_; \
    __syncthreads(); \
  } while (0)

#define GEMM_SETUP() \
  const int tid = threadIdx.x; \
  const int w = tid >> 6, l = tid & 63; \
  const int wjg = w >> 1, wcg = w & 1; \
  const int l15 = tid & 15, g = l >> 4; \
  const int swoff = (g ^ ((l15 >> 1) & 3)) * 8; \
  const int wst = w * 512; \
  const int d4 = l15 >> 2, g8 = g * 8; \
  const u32 t_lane = (u32)(l15 & 3); \
  const int sch = (l & 3) ^ ((l >> 3) & 3); \
  f32x4 acc[4][4]; \
  { const f32x4 zero_ = {0.f, 0.f, 0.f, 0.f}; \
    _Pragma("unroll") \
    for (int ji = 0; ji < 4; ++ji) \
      _Pragma("unroll") \
      for (int ci = 0; ci < 4; ++ci) acc[ji][ci] = zero_; }

// ---------------- K2: qkv GEMM (one branch-panel per block) + BN + LIF -> sp nibbles --
__global__ __launch_bounds__(512, 4) void k_qkv(
    const u16* __restrict__ Wstk, const u8* __restrict__ xsb,
    const float4* __restrict__ BNP, u8* __restrict__ sp) {
  const int jt = blockIdx.x, mt = blockIdx.y, b = blockIdx.z;
  __shared__ u16 lds[37888];                      // 26624B X + 6x8KB W = 75776 B

  GEMM_SETUP();
  XSTAGE(xsb);

  const int m0 = mt * 128;                        // == (mt/3)*384 + (mt%3)*128 in Wstk
  const u16* Wp = Wstk + (size_t)(m0 + w * 16 + (l >> 2)) * 384 + sch * 8;

  GEMM_PIPELINE();

  // epilogue: BN + 4-step LIF (acc regs = t), pack 4 spike bits -> one u8
  const int br = mt / 3;
  const int cb = (mt - br * 3) * 128;
  const int n_base = b * 1024 + jt * 64 + wjg * 16 + g;
  u8* spW = sp + (size_t)br * SPB;
  #pragma unroll
  for (int ci = 0; ci < 4; ++ci) {
    const int c_loc = wcg * 64 + ci * 16 + l15;
    float4 pr = BNP[br * 384 + cb + c_loc];       // direct L2 load
    #pragma unroll
    for (int ji = 0; ji < 4; ++ji) {
      f32x4 a = acc[ji][ci];
      u32 bits = 0;
      float vv = 0.f;
      #pragma unroll
      for (int t = 0; t < 4; ++t) {
        float z = __fadd_rn(__fmul_rn(__fsub_rn(a[t], pr.y), pr.x), pr.z);  // BN, ref order
        float h = __fadd_rn(vv, __fmul_rn(__fsub_rn(z, vv), 0.5f));          // LIF step
        bool s = h >= 1.f;
        vv = s ? 0.f : h;
        bits |= (s ? 1u : 0u) << t;
      }
      spW[(size_t)(n_base + ji * 4) * 384 + cb + c_loc] = (u8)bits;
    }
  }
}

// ---------------- K4: P GEMM + FUSED attn (k&v head-sum, LIF(0.5), q-mask) ------------
// Stage thread-map (row=tid>>3, chunk=tid&7): one 48-B chunk == one head, so the attn
// reduction + LIF scan + q-mask are fully thread-local (integer fp32 -> bit-exact).
__global__ __launch_bounds__(512, 4) void k_proj(
    const u16* __restrict__ Pw, const u8* __restrict__ sp,
    const float4* __restrict__ PP, float* __restrict__ out) {
  const int jt = blockIdx.x, mt = blockIdx.y, b = blockIdx.z;
  __shared__ u16 lds[37888];

  {                                                // fused attn + X stage
    const int tt = threadIdx.x;
    const int xn_ = tt >> 3, hd_ = tt & 7;
    const u8* qrow = sp + (size_t)(b * 1024 + jt * 64 + xn_) * 384 + hd_ * 48;
    const u8* krow = qrow + SPB;
    const u8* vrow = qrow + 2 * SPB;
    u32 qa[12], ka[12], va[12];
    #pragma unroll
    for (int i = 0; i < 3; ++i) {
      *(uint4*)&qa[i * 4] = *(const uint4*)(qrow + i * 16);
      *(uint4*)&ka[i * 4] = *(const uint4*)(krow + i * 16);
      *(uint4*)&va[i * 4] = *(const uint4*)(vrow + i * 16);
    }
    u32 m0 = 0, m1 = 0, m2 = 0, m3 = 0;
    #pragma unroll
    for (int i = 0; i < 12; ++i) {
      u32 a = ka[i] & va[i];
      m0 += a & 0x01010101u;
      m1 += (a >> 1) & 0x01010101u;
      m2 += (a >> 2) & 0x01010101u;
      m3 += (a >> 3) & 0x01010101u;
    }
    float s0 = (float)((m0 * 0x01010101u) >> 24);  // head sums per t, <= 48, exact
    float s1 = (float)((m1 * 0x01010101u) >> 24);
    float s2 = (float)((m2 * 0x01010101u) >> 24);
    float s3 = (float)((m3 * 0x01010101u) >> 24);
    float vv = 0.f;
    u32 m8 = 0;
    #pragma unroll
    for (int t = 0; t < 4; ++t) {
      float attn = (t == 0) ? s0 : (t == 1) ? s1 : (t == 2) ? s2 : s3;
      float h = __fadd_rn(vv, __fmul_rn(__fsub_rn(attn, vv), 0.5f));
      bool sk = h >= 0.5f;
      vv = sk ? 0.f : h;
      m8 |= (sk ? 1u : 0u) << t;
    }
    const u32 mm = m8 * 0x01010101u;
    u8* xd_ = (u8*)lds + xn_ * 416 + hd_ * 48;
    #pragma unroll
    for (int i = 0; i < 3; ++i) {
      uint4 wv;
      wv.x = qa[i * 4 + 0] & mm;
      wv.y = qa[i * 4 + 1] & mm;
      wv.z = qa[i * 4 + 2] & mm;
      wv.w = qa[i * 4 + 3] & mm;
      *(uint4*)(xd_ + i * 16) = wv;
    }
    __syncthreads();
  }

  GEMM_SETUP();

  const int m0 = mt * 128;
  const u16* Wp = Pw + (size_t)(m0 + w * 16 + (l >> 2)) * 384 + sch * 8;

  GEMM_PIPELINE();

  __syncthreads();                                 // all waves done with LDS buffers
  float* scr = (float*)lds;                        // 128 x 68-padded f32 tile (34.8 KB)
  const int n0im = jt * 64;
  float4 prc[4];
  #pragma unroll
  for (int ci = 0; ci < 4; ++ci) prc[ci] = PP[m0 + wcg * 64 + ci * 16 + l15];

  #pragma unroll
  for (int t = 0; t < 4; ++t) {
    #pragma unroll
    for (int ci = 0; ci < 4; ++ci) {
      const int c_loc = wcg * 64 + ci * 16 + l15;
      float4 pr = prc[ci];
      #pragma unroll
      for (int ji = 0; ji < 4; ++ji) {
        const int n_loc = wjg * 16 + ji * 4 + g;
        float zz = __fadd_rn(acc[ji][ci][t], pr.w);                        // + bias
        zz = __fadd_rn(__fmul_rn(__fsub_rn(zz, pr.y), pr.x), pr.z);        // BN, ref order
        scr[c_loc * 68 + n_loc] = zz;
      }
    }
    __syncthreads();
    #pragma unroll
    for (int it = 0; it < 4; ++it) {
      int slot = tid + it * 512;                   // 2048 slots = 128 rows x 16 float4
      int c = slot >> 4, li = slot & 15;
      float4 val = *(const float4*)&scr[c * 68 + li * 4];
      *(float4*)&out[(((size_t)(t * 16 + b) * 384) + m0 + c) * 1024 + n0im + li * 4] = val;
    }
    __syncthreads();
  }
}

extern "C" void kernel_launch(void* const* d_in, const int* in_sizes, int n_in,
                              void* d_out, int out_size, void* d_ws, size_t ws_size,
                              hipStream_t stream) {
  (void)in_sizes; (void)n_in; (void)out_size; (void)ws_size;
  const float* x   = (const float*)d_in[0];
  const float* qw  = (const float*)d_in[1];
  const float* qg  = (const float*)d_in[2];
  const float* qbt = (const float*)d_in[3];
  const float* qm  = (const float*)d_in[4];
  const float* qv  = (const float*)d_in[5];
  const float* kw  = (const float*)d_in[6];
  const float* kg  = (const float*)d_in[7];
  const float* kbt = (const float*)d_in[8];
  const float* km  = (const float*)d_in[9];
  const float* kv  = (const float*)d_in[10];
  const float* vw  = (const float*)d_in[11];
  const float* vg  = (const float*)d_in[12];
  const float* vbt = (const float*)d_in[13];
  const float* vm  = (const float*)d_in[14];
  const float* vv  = (const float*)d_in[15];
  const float* pw  = (const float*)d_in[16];
  const float* pg  = (const float*)d_in[17];
  const float* pbt = (const float*)d_in[18];
  const float* pm  = (const float*)d_in[19];
  const float* pv  = (const float*)d_in[20];
  const float* pbias = (const float*)d_in[21];

  char* ws = (char*)d_ws;
  u8*  xsb   = (u8*)ws;                     // input spikes, packed nibbles (6.3 MB)
  u8*  sp    = (u8*)(ws + 6291456);         // q,k,v spike nibbles (3 x 6.3 MB)
  u16* Wstk  = (u16*)(ws + 31457280);       // [1152][384] bf16
  u16* Pw    = (u16*)(ws + 32342016);       // [384][384] bf16
  float4* BNP = (float4*)(ws + 32636928);   // [1152]
  float4* PP  = (float4*)(ws + 32655360);   // [384]

  k_convert<<<2310, 256, 0, stream>>>(qw, kw, vw, pw, qg, qbt, qm, qv, kg, kbt, km, kv,
                                      vg, vbt, vm, vv, pg, pbt, pm, pv, pbias,
                                      Wstk, Pw, BNP, PP);
  k_lif_in<<<dim3(16, 6, 16), 256, 0, stream>>>(x, xsb);
  k_qkv<<<dim3(16, 9, 16), 512, 0, stream>>>(Wstk, xsb, BNP, sp);
  k_proj<<<dim3(16, 3, 16), 512, 0, stream>>>(Pw, sp, PP, (float*)d_out);
}

// Round 14
// 114.211 us; speedup vs baseline: 1.1288x; 1.0167x over previous
//
#include <hip/hip_runtime.h>

typedef unsigned short u16;
typedef unsigned char u8;
typedef unsigned int u32;
typedef float f32x4 __attribute__((ext_vector_type(4)));
typedef __bf16 bf16x8 __attribute__((ext_vector_type(8)));

#define SPB 6291456      // bytes per packed branch: B*N*C = 16*1024*384 (u8, 4 t-bits)

// ---- async global->LDS, 16B per lane, dest = wave-uniform base + lane*16 ----
__device__ __forceinline__ void gll16(const void* g, void* l) {
  __builtin_amdgcn_global_load_lds((const __attribute__((address_space(1))) void*)g,
                                   (__attribute__((address_space(3))) void*)l, 16, 0, 0);
}

// expand 8 packed spike-bytes (bit t) -> 8 bf16 {0,1}; perm+mul: (b0|b1<<16)*0x3F80
__device__ __forceinline__ uint4 expand8f(uint2 v, u32 t) {
  u32 a = (v.x >> t) & 0x01010101u;
  u32 b = (v.y >> t) & 0x01010101u;
  uint4 r;
  r.x = __builtin_amdgcn_perm(0u, a, 0x0C010C00u) * 0x3F80u;
  r.y = __builtin_amdgcn_perm(0u, a, 0x0C030C02u) * 0x3F80u;
  r.z = __builtin_amdgcn_perm(0u, b, 0x0C010C00u) * 0x3F80u;
  r.w = __builtin_amdgcn_perm(0u, b, 0x0C030C02u) * 0x3F80u;
  return r;
}

// ---------------- K0: weights -> bf16 (stacked q,k,v), BN params fused ----------------
__global__ __launch_bounds__(256) void k_convert(
    const float* __restrict__ qw, const float* __restrict__ kw,
    const float* __restrict__ vw, const float* __restrict__ pw,
    const float* __restrict__ qg, const float* __restrict__ qbt,
    const float* __restrict__ qm, const float* __restrict__ qv,
    const float* __restrict__ kg, const float* __restrict__ kbt,
    const float* __restrict__ km, const float* __restrict__ kv,
    const float* __restrict__ vg, const float* __restrict__ vbt,
    const float* __restrict__ vm, const float* __restrict__ vv,
    const float* __restrict__ pg, const float* __restrict__ pbt,
    const float* __restrict__ pm, const float* __restrict__ pv,
    const float* __restrict__ pbias,
    u16* __restrict__ Wstk, u16* __restrict__ Pw,
    float4* __restrict__ BNP, float4* __restrict__ PP) {
  int tid = blockIdx.x * 256 + threadIdx.x;
  if (tid < 442368) {               // Wstk[1152][384]
    int r = tid / 384, c = tid - r * 384;
    const float* src = (r < 384) ? qw : (r < 768) ? kw : vw;
    int rr = (r >= 768) ? r - 768 : (r >= 384) ? r - 384 : r;
    unsigned int u = __float_as_uint(src[rr * 384 + c]);
    u = (u + 0x7FFFu + ((u >> 16) & 1u)) >> 16;   // RNE to bf16
    Wstk[tid] = (u16)u;
  } else if (tid < 589824) {        // Pw[384][384]
    int i = tid - 442368;
    unsigned int u = __float_as_uint(pw[i]);
    u = (u + 0x7FFFu + ((u >> 16) & 1u)) >> 16;
    Pw[i] = (u16)u;
  } else if (tid < 590976) {        // BNP[1152] = {inv, mean, beta, -}
    int r = tid - 589824;
    int br = r / 384, ch = r - br * 384;
    const float* g  = (br == 0) ? qg  : (br == 1) ? kg  : vg;
    const float* bt = (br == 0) ? qbt : (br == 1) ? kbt : vbt;
    const float* m  = (br == 0) ? qm  : (br == 1) ? km  : vm;
    const float* va = (br == 0) ? qv  : (br == 1) ? kv  : vv;
    float inv = g[ch] / sqrtf(va[ch] + 1e-5f);
    BNP[r] = make_float4(inv, m[ch], bt[ch], 0.f);
  } else if (tid < 591360) {        // PP[384] = {inv, mean, beta, bias}
    int ch = tid - 590976;
    float inv = pg[ch] / sqrtf(pv[ch] + 1e-5f);
    PP[ch] = make_float4(inv, pm[ch], pbt[ch], pbias[ch]);
  }
}

// ---------------- K1: input LIF -> packed nibble xsb[(b*1024+n)*384 + c] --------------
// float4 reads along n (4x fewer load instrs than scalar); phase-2 transpose unchanged.
__global__ __launch_bounds__(256) void k_lif_in(const float* __restrict__ x, u8* __restrict__ xsb) {
  const int nt = blockIdx.x, ct = blockIdx.y, b = blockIdx.z;
  const int tid = threadIdx.x;
  const int n4 = tid & 15, cL = tid >> 4;     // 16 n-quads x 16 c-lanes
  const int c0 = ct * 64, n0 = nt * 64;
  __shared__ u32 nibs[64 * 65];               // [n][c], 65-pad -> 2-way max on writes
  float v[4][4];
  u32 nib[4][4];
  #pragma unroll
  for (int it = 0; it < 4; ++it)
    #pragma unroll
    for (int ns = 0; ns < 4; ++ns) { v[it][ns] = 0.f; nib[it][ns] = 0u; }
  for (int t = 0; t < 4; ++t) {
    #pragma unroll
    for (int it = 0; it < 4; ++it) {
      const float4 xv = *(const float4*)&x[(size_t)(((t * 16 + b) * 384 + c0 + cL + it * 16)) * 1024
                                           + n0 + n4 * 4];
      #pragma unroll
      for (int ns = 0; ns < 4; ++ns) {
        float xe = (ns == 0) ? xv.x : (ns == 1) ? xv.y : (ns == 2) ? xv.z : xv.w;
        float vv = v[it][ns];
        float h = __fadd_rn(vv, __fmul_rn(__fsub_rn(xe, vv), 0.5f));  // v + (x-v)/2, exact order
        bool s = h >= 1.f;
        v[it][ns] = s ? 0.f : h;
        nib[it][ns] |= (s ? 1u : 0u) << t;
      }
    }
  }
  #pragma unroll
  for (int it = 0; it < 4; ++it)
    #pragma unroll
    for (int ns = 0; ns < 4; ++ns)
      nibs[(n4 * 4 + ns) * 65 + cL + it * 16] = nib[it][ns];
  __syncthreads();
  const int n = tid >> 2, ch = tid & 3;
  u32 w0[4];
  #pragma unroll
  for (int q = 0; q < 4; ++q) {
    u32 acc = 0;
    #pragma unroll
    for (int i = 0; i < 4; ++i)
      acc |= (nibs[n * 65 + ch * 16 + q * 4 + i] & 0xFu) << (8 * i);
    w0[q] = acc;
  }
  *(uint4*)(xsb + ((size_t)(b * 1024 + n0 + n)) * 384 + c0 + ch * 16) =
      make_uint4(w0[0], w0[1], w0[2], w0[3]);
}

// ======================================================================================
// GEMM core v9 (unique-A waves): BM=128 c, BN=256 j (64 n x 4 t), K=384 full, 8 waves.
// Wave w owns 8 n-rows (32 j) and ALL 128 c: ji=2, ci=8 -> 16 MFMA/wave/tile, and each
// wave's A-expand is UNIQUE (v8's wcg pairs expanded identical data -> half the expand
// VALU was waste; issue-port is the measured binding resource, VALU+MFMA ~96%).
// X packed-resident in LDS (26 KB, 416B-padded rows), expanded to bf16 on read.
// W pipelined: 6 x 8KB ring, 1 gll16/thread/tile, 4 tiles in flight, vmcnt(2),
// TWO K-tiles per barrier interval (R13). LDS 75776 B -> 2 blocks/CU, 4 waves/SIMD.
// ======================================================================================
#define XLDS_U16 13312                 // 26624 B X region (64 rows x 416 B)
#define WSLOT_U16 4096                 // 8 KB per W buffer slot

#define GISSUE(kt) gll16(Wp + (kt) * 32, &lds[XLDS_U16 + ((kt) % 6) * WSLOT_U16 + wst])

#define SYNCP(n) do { \
    asm volatile("s_waitcnt vmcnt(" #n ")" ::: "memory"); \
    __builtin_amdgcn_s_barrier(); \
    asm volatile("" ::: "memory"); \
  } while (0)

#define COMPUTE(kt) do { \
    const u8* xb_ = (const u8*)lds; \
    const u16* wb_ = &lds[XLDS_U16 + ((kt) % 6) * WSLOT_U16]; \
    bf16x8 ax[2]; \
    _Pragma("unroll") \
    for (int ji = 0; ji < 2; ++ji) { \
      uint2 xr_ = *(const uint2*)(xb_ + (w * 8 + ji * 4 + d4) * 416 + (kt) * 32 + g8); \
      uint4 e_ = expand8f(xr_, t_lane); \
      ax[ji] = *(bf16x8*)&e_; \
    } \
    __builtin_amdgcn_s_setprio(1); \
    _Pragma("unroll") \
    for (int ci = 0; ci < 8; ++ci) { \
      bf16x8 bw_ = *(const bf16x8*)&wb_[(ci * 16 + l15) * 32 + swoff]; \
      _Pragma("unroll") \
      for (int ji = 0; ji < 2; ++ji) \
        acc[ji][ci] = __builtin_amdgcn_mfma_f32_16x16x32_bf16(ax[ji], bw_, acc[ji][ci], 0, 0, 0); \
    } \
    __builtin_amdgcn_s_setprio(0); \
  } while (0)

#define GEMM_PIPELINE() do { \
    GISSUE(0); GISSUE(1); GISSUE(2); GISSUE(3); \
    SYNCP(2); GISSUE(4);  GISSUE(5);  COMPUTE(0);  COMPUTE(1); \
    SYNCP(2); GISSUE(6);  GISSUE(7);  COMPUTE(2);  COMPUTE(3); \
    SYNCP(2); GISSUE(8);  GISSUE(9);  COMPUTE(4);  COMPUTE(5); \
    SYNCP(2); GISSUE(10); GISSUE(11); COMPUTE(6);  COMPUTE(7); \
    SYNCP(2); COMPUTE(8);  COMPUTE(9); \
    SYNCP(0); COMPUTE(10); COMPUTE(11); \
  } while (0)

// stage packed X strip (64 n x 384 B) into padded LDS rows (416 B), then sync
#define XSTAGE(XSRC) do { \
    const int xn_ = tid >> 3, xcp_ = tid & 7; \
    const u8* xs_ = (XSRC) + (size_t)(b * 1024 + jt * 64 + xn_) * 384 + xcp_ * 48; \
    u8* xd_ = (u8*)lds + xn_ * 416 + xcp_ * 48; \
    uint4 v0_ = *(const uint4*)(xs_); \
    uint4 v1_ = *(const uint4*)(xs_ + 16); \
    uint4 v2_ = *(const uint4*)(xs_ + 32); \
    *(uint4*)(xd_) = v0_; *(uint4*)(xd_ + 16) = v1_; *(uint4*)(xd_ + 32) = v2_; \
    __syncthreads(); \
  } while (0)

#define GEMM_SETUP() \
  const int tid = threadIdx.x; \
  const int w = tid >> 6, l = tid & 63; \
  const int l15 = tid & 15, g = l >> 4; \
  const int swoff = (g ^ ((l15 >> 1) & 3)) * 8; \
  const int wst = w * 512; \
  const int d4 = l15 >> 2, g8 = g * 8; \
  const u32 t_lane = (u32)(l15 & 3); \
  const int sch = (l & 3) ^ ((l >> 3) & 3); \
  f32x4 acc[2][8]; \
  { const f32x4 zero_ = {0.f, 0.f, 0.f, 0.f}; \
    _Pragma("unroll") \
    for (int ji = 0; ji < 2; ++ji) \
      _Pragma("unroll") \
      for (int ci = 0; ci < 8; ++ci) acc[ji][ci] = zero_; }

// ---------------- K2: qkv GEMM (one branch-panel per block) + BN + LIF -> sp nibbles --
__global__ __launch_bounds__(512, 4) void k_qkv(
    const u16* __restrict__ Wstk, const u8* __restrict__ xsb,
    const float4* __restrict__ BNP, u8* __restrict__ sp) {
  const int jt = blockIdx.x, mt = blockIdx.y, b = blockIdx.z;
  __shared__ u16 lds[37888];                      // 26624B X + 6x8KB W = 75776 B

  GEMM_SETUP();
  XSTAGE(xsb);

  const int m0 = mt * 128;                        // == (mt/3)*384 + (mt%3)*128 in Wstk
  const u16* Wp = Wstk + (size_t)(m0 + w * 16 + (l >> 2)) * 384 + sch * 8;

  GEMM_PIPELINE();

  // epilogue: BN + 4-step LIF (acc regs = t), pack 4 spike bits -> one u8
  const int br = mt / 3;
  const int cb = (mt - br * 3) * 128;
  const int n_base = b * 1024 + jt * 64 + w * 8 + g;
  u8* spW = sp + (size_t)br * SPB;
  #pragma unroll
  for (int ci = 0; ci < 8; ++ci) {
    const int c_loc = ci * 16 + l15;
    float4 pr = BNP[br * 384 + cb + c_loc];       // direct L2 load
    #pragma unroll
    for (int ji = 0; ji < 2; ++ji) {
      f32x4 a = acc[ji][ci];
      u32 bits = 0;
      float vv = 0.f;
      #pragma unroll
      for (int t = 0; t < 4; ++t) {
        float z = __fadd_rn(__fmul_rn(__fsub_rn(a[t], pr.y), pr.x), pr.z);  // BN, ref order
        float h = __fadd_rn(vv, __fmul_rn(__fsub_rn(z, vv), 0.5f));          // LIF step
        bool s = h >= 1.f;
        vv = s ? 0.f : h;
        bits |= (s ? 1u : 0u) << t;
      }
      spW[(size_t)(n_base + ji * 4) * 384 + cb + c_loc] = (u8)bits;
    }
  }
}

// ---------------- K4: P GEMM + FUSED attn (k&v head-sum, LIF(0.5), q-mask) ------------
// Stage thread-map (row=tid>>3, chunk=tid&7): one 48-B chunk == one head, so the attn
// reduction + LIF scan + q-mask are fully thread-local (integer fp32 -> bit-exact).
__global__ __launch_bounds__(512, 4) void k_proj(
    const u16* __restrict__ Pw, const u8* __restrict__ sp,
    const float4* __restrict__ PP, float* __restrict__ out) {
  const int jt = blockIdx.x, mt = blockIdx.y, b = blockIdx.z;
  __shared__ u16 lds[37888];

  {                                                // fused attn + X stage
    const int tt = threadIdx.x;
    const int xn_ = tt >> 3, hd_ = tt & 7;
    const u8* qrow = sp + (size_t)(b * 1024 + jt * 64 + xn_) * 384 + hd_ * 48;
    const u8* krow = qrow + SPB;
    const u8* vrow = qrow + 2 * SPB;
    u32 qa[12], ka[12], va[12];
    #pragma unroll
    for (int i = 0; i < 3; ++i) {
      *(uint4*)&qa[i * 4] = *(const uint4*)(qrow + i * 16);
      *(uint4*)&ka[i * 4] = *(const uint4*)(krow + i * 16);
      *(uint4*)&va[i * 4] = *(const uint4*)(vrow + i * 16);
    }
    u32 m0 = 0, m1 = 0, m2 = 0, m3 = 0;
    #pragma unroll
    for (int i = 0; i < 12; ++i) {
      u32 a = ka[i] & va[i];
      m0 += a & 0x01010101u;
      m1 += (a >> 1) & 0x01010101u;
      m2 += (a >> 2) & 0x01010101u;
      m3 += (a >> 3) & 0x01010101u;
    }
    float s0 = (float)((m0 * 0x01010101u) >> 24);  // head sums per t, <= 48, exact
    float s1 = (float)((m1 * 0x01010101u) >> 24);
    float s2 = (float)((m2 * 0x01010101u) >> 24);
    float s3 = (float)((m3 * 0x01010101u) >> 24);
    float vv = 0.f;
    u32 m8 = 0;
    #pragma unroll
    for (int t = 0; t < 4; ++t) {
      float attn = (t == 0) ? s0 : (t == 1) ? s1 : (t == 2) ? s2 : s3;
      float h = __fadd_rn(vv, __fmul_rn(__fsub_rn(attn, vv), 0.5f));
      bool sk = h >= 0.5f;
      vv = sk ? 0.f : h;
      m8 |= (sk ? 1u : 0u) << t;
    }
    const u32 mm = m8 * 0x01010101u;
    u8* xd_ = (u8*)lds + xn_ * 416 + hd_ * 48;
    #pragma unroll
    for (int i = 0; i < 3; ++i) {
      uint4 wv;
      wv.x = qa[i * 4 + 0] & mm;
      wv.y = qa[i * 4 + 1] & mm;
      wv.z = qa[i * 4 + 2] & mm;
      wv.w = qa[i * 4 + 3] & mm;
      *(uint4*)(xd_ + i * 16) = wv;
    }
    __syncthreads();
  }

  GEMM_SETUP();

  const int m0 = mt * 128;
  const u16* Wp = Pw + (size_t)(m0 + w * 16 + (l >> 2)) * 384 + sch * 8;

  GEMM_PIPELINE();

  __syncthreads();                                 // all waves done with LDS buffers
  float* scr = (float*)lds;                        // 128 x 68-padded f32 tile (34.8 KB)
  const int n0im = jt * 64;
  float4 prc[8];
  #pragma unroll
  for (int ci = 0; ci < 8; ++ci) prc[ci] = PP[m0 + ci * 16 + l15];

  #pragma unroll
  for (int t = 0; t < 4; ++t) {
    #pragma unroll
    for (int ci = 0; ci < 8; ++ci) {
      const int c_loc = ci * 16 + l15;
      float4 pr = prc[ci];
      #pragma unroll
      for (int ji = 0; ji < 2; ++ji) {
        const int n_loc = w * 8 + ji * 4 + g;
        float zz = __fadd_rn(acc[ji][ci][t], pr.w);                        // + bias
        zz = __fadd_rn(__fmul_rn(__fsub_rn(zz, pr.y), pr.x), pr.z);        // BN, ref order
        scr[c_loc * 68 + n_loc] = zz;
      }
    }
    __syncthreads();
    #pragma unroll
    for (int it = 0; it < 4; ++it) {
      int slot = tid + it * 512;                   // 2048 slots = 128 rows x 16 float4
      int c = slot >> 4, li = slot & 15;
      float4 val = *(const float4*)&scr[c * 68 + li * 4];
      *(float4*)&out[(((size_t)(t * 16 + b) * 384) + m0 + c) * 1024 + n0im + li * 4] = val;
    }
    __syncthreads();
  }
}

extern "C" void kernel_launch(void* const* d_in, const int* in_sizes, int n_in,
                              void* d_out, int out_size, void* d_ws, size_t ws_size,
                              hipStream_t stream) {
  (void)in_sizes; (void)n_in; (void)out_size; (void)ws_size;
  const float* x   = (const float*)d_in[0];
  const float* qw  = (const float*)d_in[1];
  const float* qg  = (const float*)d_in[2];
  const float* qbt = (const float*)d_in[3];
  const float* qm  = (const float*)d_in[4];
  const float* qv  = (const float*)d_in[5];
  const float* kw  = (const float*)d_in[6];
  const float* kg  = (const float*)d_in[7];
  const float* kbt = (const float*)d_in[8];
  const float* km  = (const float*)d_in[9];
  const float* kv  = (const float*)d_in[10];
  const float* vw  = (const float*)d_in[11];
  const float* vg  = (const float*)d_in[12];
  const float* vbt = (const float*)d_in[13];
  const float* vm  = (const float*)d_in[14];
  const float* vv  = (const float*)d_in[15];
  const float* pw  = (const float*)d_in[16];
  const float* pg  = (const float*)d_in[17];
  const float* pbt = (const float*)d_in[18];
  const float* pm  = (const float*)d_in[19];
  const float* pv  = (const float*)d_in[20];
  const float* pbias = (const float*)d_in[21];

  char* ws = (char*)d_ws;
  u8*  xsb   = (u8*)ws;                     // input spikes, packed nibbles (6.3 MB)
  u8*  sp    = (u8*)(ws + 6291456);         // q,k,v spike nibbles (3 x 6.3 MB)
  u16* Wstk  = (u16*)(ws + 31457280);       // [1152][384] bf16
  u16* Pw    = (u16*)(ws + 32342016);       // [384][384] bf16
  float4* BNP = (float4*)(ws + 32636928);   // [1152]
  float4* PP  = (float4*)(ws + 32655360);   // [384]

  k_convert<<<2310, 256, 0, stream>>>(qw, kw, vw, pw, qg, qbt, qm, qv, kg, kbt, km, kv,
                                      vg, vbt, vm, vv, pg, pbt, pm, pv, pbias,
                                      Wstk, Pw, BNP, PP);
  k_lif_in<<<dim3(16, 6, 16), 256, 0, stream>>>(x, xsb);
  k_qkv<<<dim3(16, 9, 16), 512, 0, stream>>>(Wstk, xsb, BNP, sp);
  k_proj<<<dim3(16, 3, 16), 512, 0, stream>>>(Pw, sp, PP, (float*)d_out);
}